// Round 2
// baseline (2341.214 us; speedup 1.0000x reference)
//
#include <hip/hip_runtime.h>
#include <hip/hip_bf16.h>

#define NU 8192
#define NI 4096
#define DE 64
#define ELL_U 80
#define ELL_I 112
#define EPSF 1e-7f

#define NBLK 1024
#define NTHR 256
#define TOTTHR (NBLK * NTHR) /* 262144 threads, 4096 waves */
#define NWAVE (TOTTHR / 64)

typedef unsigned short u16;
typedef unsigned int u32;

__device__ __forceinline__ float b2f(__hip_bfloat16 x) { return __bfloat162float(x); }

struct FArgs {
    const void* Hp; const void* ue; const void* ie;
    const void* w0; const void* b0; const void* w1; const void* b1;
    int* flag; int* bar; int* cnt_u; int* cnt_i; u16* idx_u; u16* idx_i;
    float* a_f; float* p_f; float* b_f; float* q_f;
    float* dv_u; float* de1sq_u; float* de2sq_u;
    float* dv_i; float* de1sq_i; float* de2sq_i;
    float* Xu; float* Xi; float* Xsu; float* Xsi;
    float* T1u; float* TAu; float* TBu;
    float* T1i; float* TAi; float* TBi;
    void* outp;
};

struct Job {
    const int* cnt; const u16* idx; int ell; int nrows;
    const float* src; float* dst; const float* evec; const float* aux;
    const float* xin; const float* dvv; float* xnext; float* xsout;
    size_t obase; int coloff;
};

// ---- self-contained grid barrier (no cooperative runtime) ----
// Release: threadfence (agent acq_rel -> buffer_wbl2 flushes this XCD's L2; all
// block threads' stores already reached L2 via the waitcnt at __syncthreads).
// Arrive: device-scope atomic add. Spin: agent atomic load (bypasses local L2)
// with s_sleep to limit fabric traffic. Acquire: threadfence -> buffer_inv so
// subsequent reads on this CU can't hit stale L1/L2 lines.
__device__ __forceinline__ void gbar(int* bar, int& epoch) {
    __syncthreads();
    epoch += NBLK;
    if (threadIdx.x == 0) {
        __threadfence();
        __hip_atomic_fetch_add(bar, 1, __ATOMIC_RELEASE, __HIP_MEMORY_SCOPE_AGENT);
        while (__hip_atomic_load(bar, __ATOMIC_RELAXED, __HIP_MEMORY_SCOPE_AGENT) < epoch)
            __builtin_amdgcn_s_sleep(4);
        __threadfence();
    }
    __syncthreads();
}

// scalar per-thread SpMV row (int or float source)
__device__ __forceinline__ float spmv_row(int n, const u16* __restrict__ ip,
                                          const void* __restrict__ s, int isint) {
    float a0 = 0.f, a1 = 0.f, a2 = 0.f, a3 = 0.f;
    int p = 0;
    if (isint) {
        const int* sv = (const int*)s;
        for (; p + 4 <= n; p += 4) {
            ushort4 cc = *(const ushort4*)(ip + p);
            a0 += (float)sv[cc.x]; a1 += (float)sv[cc.y];
            a2 += (float)sv[cc.z]; a3 += (float)sv[cc.w];
        }
        for (; p < n; p++) a0 += (float)sv[ip[p]];
    } else {
        const float* sv = (const float*)s;
        for (; p + 4 <= n; p += 4) {
            ushort4 cc = *(const ushort4*)(ip + p);
            a0 += sv[cc.x]; a1 += sv[cc.y]; a2 += sv[cc.z]; a3 += sv[cc.w];
        }
        for (; p < n; p++) a0 += sv[ip[p]];
    }
    return (a0 + a1) + (a2 + a3);
}

// one wave gathers/accumulates one 64-col row; 8 loads in flight
__device__ __forceinline__ float gather_row(int n, const u16* __restrict__ ip,
                                            const float* __restrict__ src, int lane) {
    float a0 = 0.f, a1 = 0.f, a2 = 0.f, a3 = 0.f;
    float a4 = 0.f, a5 = 0.f, a6 = 0.f, a7 = 0.f;
    int p = 0;
    if (n >= 8) {
        ushort4 cA = *(const ushort4*)(ip);
        ushort4 cB = *(const ushort4*)(ip + 4);
        while (p + 8 <= n) {
            float g0 = src[((size_t)cA.x << 6) + lane];
            float g1 = src[((size_t)cA.y << 6) + lane];
            float g2 = src[((size_t)cA.z << 6) + lane];
            float g3 = src[((size_t)cA.w << 6) + lane];
            float g4 = src[((size_t)cB.x << 6) + lane];
            float g5 = src[((size_t)cB.y << 6) + lane];
            float g6 = src[((size_t)cB.z << 6) + lane];
            float g7 = src[((size_t)cB.w << 6) + lane];
            p += 8;
            // prefetch next batch's indices (overreads <=16B into row padding)
            cA = *(const ushort4*)(ip + p);
            cB = *(const ushort4*)(ip + p + 4);
            a0 += g0; a1 += g1; a2 += g2; a3 += g3;
            a4 += g4; a5 += g5; a6 += g6; a7 += g7;
        }
    }
    if (p + 4 <= n) {
        ushort4 cc = *(const ushort4*)(ip + p);
        a0 += src[((size_t)cc.x << 6) + lane];
        a1 += src[((size_t)cc.y << 6) + lane];
        a2 += src[((size_t)cc.z << 6) + lane];
        a3 += src[((size_t)cc.w << 6) + lane];
        p += 4;
    }
    for (; p < n; p++) a4 += src[((size_t)ip[p] << 6) + lane];
    return ((a0 + a1) + (a2 + a3)) + ((a4 + a5) + (a6 + a7));
}

// one SpMM phase over both channels; waves grid-stride the 12288 rows
__device__ __forceinline__ void spmm_phase(const Job& j0, const Job& j1, int mode,
                                           const void* w, const void* bias, void* outp,
                                           int isbf, int gwave, int lane) {
    int ntot = j0.nrows + j1.nrows;
    for (int rr = gwave; rr < ntot; rr += NWAVE) {
        bool first = rr < j0.nrows;
        const Job& J = first ? j0 : j1;
        int row = first ? rr : rr - j0.nrows;
        int n = min(J.cnt[row], J.ell);
        const u16* ip = J.idx + (size_t)row * J.ell;
        float acc = gather_row(n, ip, J.src, lane);
        size_t o = ((size_t)row << 6) + lane;
        if (mode == 0) {
            J.dst[o] = acc;
        } else if (mode == 1) {
            J.dst[o] = J.evec[row] * acc;
        } else if (mode == 2) {
            J.dst[o] = acc + J.evec[row] * J.aux[o];
        } else {
            // M = dv*acc + X ; Xnext = M @ w + b ; emit output in detected dtype
            float dvr = J.dvv[row];
            float m = dvr * acc + J.xin[o];
            float x0, x1 = 0.f, x2 = 0.f, x3 = 0.f;
            if (isbf) {
                const __hip_bfloat16* __restrict__ wp = (const __hip_bfloat16*)w;
                x0 = b2f(((const __hip_bfloat16*)bias)[lane]);
                for (int k = 0; k < 64; k += 4) {
                    x0 = fmaf(__shfl(m, k, 64), b2f(wp[(k << 6) + lane]), x0);
                    x1 = fmaf(__shfl(m, k + 1, 64), b2f(wp[((k + 1) << 6) + lane]), x1);
                    x2 = fmaf(__shfl(m, k + 2, 64), b2f(wp[((k + 2) << 6) + lane]), x2);
                    x3 = fmaf(__shfl(m, k + 3, 64), b2f(wp[((k + 3) << 6) + lane]), x3);
                }
            } else {
                const float* __restrict__ wp = (const float*)w;
                x0 = ((const float*)bias)[lane];
                for (int k = 0; k < 64; k += 4) {
                    x0 = fmaf(__shfl(m, k, 64), wp[(k << 6) + lane], x0);
                    x1 = fmaf(__shfl(m, k + 1, 64), wp[((k + 1) << 6) + lane], x1);
                    x2 = fmaf(__shfl(m, k + 2, 64), wp[((k + 2) << 6) + lane], x2);
                    x3 = fmaf(__shfl(m, k + 3, 64), wp[((k + 3) << 6) + lane], x3);
                }
            }
            float xn = (x0 + x1) + (x2 + x3);
            J.xnext[o] = xn;
            J.xsout[o] = dvr * xn; // dv-premultiplied for next layer's s1
            size_t oo = J.obase + (size_t)row * 192 + J.coloff + lane;
            if (isbf) ((__hip_bfloat16*)outp)[oo] = __float2bfloat16(xn);
            else ((float*)outp)[oo] = xn;
        }
    }
}

__device__ __forceinline__ Job mkjob(const int* cnt, const u16* idx, int ell, int nrows,
                                     const float* src, float* dst, const float* evec,
                                     const float* aux, const float* xin, const float* dvv,
                                     float* xnext, float* xsout, size_t obase, int coloff) {
    Job J;
    J.cnt = cnt; J.idx = idx; J.ell = ell; J.nrows = nrows;
    J.src = src; J.dst = dst; J.evec = evec; J.aux = aux;
    J.xin = xin; J.dvv = dvv; J.xnext = xnext; J.xsout = xsout;
    J.obase = obase; J.coloff = coloff;
    return J;
}

// ---------------- init: zero counters / flag / barrier ----------------

__global__ __launch_bounds__(256) void init_k(int* cnt_u, int* cnt_i, int* flag, int* bar) {
    int t = blockIdx.x * 256 + threadIdx.x;
    if (t == 0) { flag[0] = 0; bar[0] = 0; }
    if (t < NU) cnt_u[t] = 0;
    int s = t - NU;
    if (s >= 0 && s < NI) cnt_i[s] = 0;
}

// ---------------- the single fused kernel (self-barriered) ----------------

__global__ __launch_bounds__(NTHR, 4) void fused(FArgs A) {
    const int tid = blockIdx.x * NTHR + threadIdx.x;
    const int lane = threadIdx.x & 63;
    const int gwave = tid >> 6;
    int ep = 0;

    // ---- P1: dtype probe over first 512KB of H ----
    // fp32 words are 0x00000000/0x3F800000 (low u16 always 0); bf16 pairs expose
    // 0x3F80 in the low u16 for even-col nnz (benign same-value race).
    if (tid < 131072) {
        u32 w = ((const u32*)A.Hp)[tid];
        if ((w & 0xFFFFu) == 0x3F80u) A.flag[0] = 1;
    }
    gbar(A.bar, ep);
    const int isbf = A.flag[0];

    // ---- P2: fill ELL lists for H and H^T (grid-stride, 8 elems/thread/iter) ----
    for (int t = tid; t < NU * NI / 8; t += TOTTHR) {
        int flat = t << 3;
        int i = flat >> 12;    // user row
        int j0 = flat & 4095;  // col base
        u32 words[8];
        if (isbf) {
            uint4 v = ((const uint4*)A.Hp)[t];
            u32 p4[4] = {v.x, v.y, v.z, v.w};
#pragma unroll
            for (int q = 0; q < 4; q++) {
                words[2 * q] = p4[q] & 0xFFFFu;
                words[2 * q + 1] = p4[q] >> 16;
            }
        } else {
            uint4 a = ((const uint4*)A.Hp)[2 * t];
            uint4 b = ((const uint4*)A.Hp)[2 * t + 1];
            words[0] = a.x; words[1] = a.y; words[2] = a.z; words[3] = a.w;
            words[4] = b.x; words[5] = b.y; words[6] = b.z; words[7] = b.w;
        }
#pragma unroll
        for (int e = 0; e < 8; e++) {
            if (words[e]) {
                int j = j0 + e;
                int pu = atomicAdd(&A.cnt_u[i], 1);
                if (pu < ELL_U) A.idx_u[i * ELL_U + pu] = (u16)j;
                int pi = atomicAdd(&A.cnt_i[j], 1);
                if (pi < ELL_I) A.idx_i[j * ELL_I + pi] = (u16)i;
            }
        }
    }
    gbar(A.bar, ep);

    // ---- P3: a = H^T r (item rows, int src), p = H c (user rows, int src) ----
    if (tid < NI) {
        int n = min(A.cnt_i[tid], ELL_I);
        A.a_f[tid] = spmv_row(n, A.idx_i + (size_t)tid * ELL_I, A.cnt_u, 1);
    } else {
        int r = tid - NI;
        if (r < NU) {
            int n = min(A.cnt_u[r], ELL_U);
            A.p_f[r] = spmv_row(n, A.idx_u + (size_t)r * ELL_U, A.cnt_i, 1);
        }
    }
    gbar(A.bar, ep);

    // ---- P4: b = H a (user rows), q = H^T p (item rows) ----
    if (tid < NU) {
        int n = min(A.cnt_u[tid], ELL_U);
        A.b_f[tid] = spmv_row(n, A.idx_u + (size_t)tid * ELL_U, A.a_f, 0);
    } else {
        int r = tid - NU;
        if (r < NI) {
            int n = min(A.cnt_i[r], ELL_I);
            A.q_f[r] = spmv_row(n, A.idx_i + (size_t)r * ELL_I, A.p_f, 0);
        }
    }
    gbar(A.bar, ep);

    // ---- P5: degree vectors + fp32 working copies + layer-0 output cols ----
    if (tid < NU) {
        float r = (float)A.cnt_u[tid];
        A.dv_u[tid] = 1.0f / sqrtf(r + A.b_f[tid] + EPSF);
        A.de1sq_i[tid] = 1.0f / (r + EPSF);
        A.de2sq_i[tid] = 1.0f / (A.b_f[tid] + EPSF);
    }
    if (tid < NI) {
        float cdeg = (float)A.cnt_i[tid];
        A.dv_i[tid] = 1.0f / sqrtf(cdeg + A.q_f[tid] + EPSF);
        A.de1sq_u[tid] = 1.0f / (cdeg + EPSF);
        A.de2sq_u[tid] = 1.0f / (A.q_f[tid] + EPSF);
    }
    for (int t = tid; t < (NU + NI) * DE; t += TOTTHR) {
        if (t < NU * DE) {
            int i = t >> 6, l = t & 63;
            float v = isbf ? b2f(((const __hip_bfloat16*)A.ue)[t]) : ((const float*)A.ue)[t];
            A.Xu[t] = v;
            float dv = 1.0f / sqrtf((float)A.cnt_u[i] + A.b_f[i] + EPSF);
            A.Xsu[t] = dv * v;
            size_t o = (size_t)i * 192 + l;
            if (isbf) ((__hip_bfloat16*)A.outp)[o] = __float2bfloat16(v);
            else ((float*)A.outp)[o] = v;
        } else {
            int s = t - NU * DE;
            int i = s >> 6, l = s & 63;
            float v = isbf ? b2f(((const __hip_bfloat16*)A.ie)[s]) : ((const float*)A.ie)[s];
            A.Xi[s] = v;
            float dv = 1.0f / sqrtf((float)A.cnt_i[i] + A.q_f[i] + EPSF);
            A.Xsi[s] = dv * v;
            size_t o = (size_t)(NU + i) * 192 + l;
            if (isbf) ((__hip_bfloat16*)A.outp)[o] = __float2bfloat16(v);
            else ((float*)A.outp)[o] = v;
        }
    }
    gbar(A.bar, ep);

    // ---- P6..: the 12 SpMM phases (6 per layer, both channels each) ----
    for (int layer = 0; layer < 2; ++layer) {
        const void* w = layer ? A.w1 : A.w0;
        const void* bb = layer ? A.b1 : A.b0;
        int coloff = 64 + 64 * layer;

        // s1: T1 = A^T Xs
        spmm_phase(mkjob(A.cnt_i, A.idx_i, ELL_I, NI, A.Xsu, A.T1u, 0, 0, 0, 0, 0, 0, 0, 0),
                   mkjob(A.cnt_u, A.idx_u, ELL_U, NU, A.Xsi, A.T1i, 0, 0, 0, 0, 0, 0, 0, 0),
                   0, w, bb, A.outp, isbf, gwave, lane);
        gbar(A.bar, ep);
        // s2: T2 = A T1
        spmm_phase(mkjob(A.cnt_u, A.idx_u, ELL_U, NU, A.T1u, A.TAu, 0, 0, 0, 0, 0, 0, 0, 0),
                   mkjob(A.cnt_i, A.idx_i, ELL_I, NI, A.T1i, A.TAi, 0, 0, 0, 0, 0, 0, 0, 0),
                   0, w, bb, A.outp, isbf, gwave, lane);
        gbar(A.bar, ep);
        // s3: T3s = de2sq o (A^T T2)
        spmm_phase(mkjob(A.cnt_i, A.idx_i, ELL_I, NI, A.TAu, A.TBu, A.de2sq_u, 0, 0, 0, 0, 0, 0, 0),
                   mkjob(A.cnt_u, A.idx_u, ELL_U, NU, A.TAi, A.TBi, A.de2sq_i, 0, 0, 0, 0, 0, 0, 0),
                   1, w, bb, A.outp, isbf, gwave, lane);
        gbar(A.bar, ep);
        // s4: T4 = A T3s
        spmm_phase(mkjob(A.cnt_u, A.idx_u, ELL_U, NU, A.TBu, A.TAu, 0, 0, 0, 0, 0, 0, 0, 0),
                   mkjob(A.cnt_i, A.idx_i, ELL_I, NI, A.TBi, A.TAi, 0, 0, 0, 0, 0, 0, 0, 0),
                   0, w, bb, A.outp, isbf, gwave, lane);
        gbar(A.bar, ep);
        // s5: S = A^T T4 + de1sq o T1
        spmm_phase(mkjob(A.cnt_i, A.idx_i, ELL_I, NI, A.TAu, A.TBu, A.de1sq_u, A.T1u, 0, 0, 0, 0, 0, 0),
                   mkjob(A.cnt_u, A.idx_u, ELL_U, NU, A.TAi, A.TBi, A.de1sq_i, A.T1i, 0, 0, 0, 0, 0, 0),
                   2, w, bb, A.outp, isbf, gwave, lane);
        gbar(A.bar, ep);
        // s6: M = dv o (A S) + X ; Xnext = M w + b ; Xs = dv o Xnext ; emit output
        spmm_phase(mkjob(A.cnt_u, A.idx_u, ELL_U, NU, A.TBu, 0, 0, 0, A.Xu, A.dv_u, A.Xu, A.Xsu,
                         0, coloff),
                   mkjob(A.cnt_i, A.idx_i, ELL_I, NI, A.TBi, 0, 0, 0, A.Xi, A.dv_i, A.Xi, A.Xsi,
                         (size_t)NU * 192, coloff),
                   3, w, bb, A.outp, isbf, gwave, lane);
        if (layer == 0) gbar(A.bar, ep);  // Xsu/Xsi feed next layer's s1
    }
}

// ---------------- host ----------------

extern "C" void kernel_launch(void* const* d_in, const int* in_sizes, int n_in,
                              void* d_out, int out_size, void* d_ws, size_t ws_size,
                              hipStream_t stream) {
    char* ws = (char*)d_ws;
    size_t off = 0;
    auto alloc = [&](size_t bytes) -> char* {
        char* p = ws + off;
        off = (off + bytes + 255) & ~(size_t)255;
        return p;
    };

    FArgs A;
    A.Hp = d_in[0];
    A.ue = d_in[1];
    A.ie = d_in[2];
    A.w0 = d_in[3];
    A.b0 = d_in[4];
    A.w1 = d_in[5];
    A.b1 = d_in[6];

    A.flag = (int*)alloc(256);
    A.bar = (int*)alloc(256);
    A.cnt_u = (int*)alloc(NU * 4);
    A.cnt_i = (int*)alloc(NI * 4);
    A.idx_u = (u16*)alloc((size_t)NU * ELL_U * 2);
    A.idx_i = (u16*)alloc((size_t)NI * ELL_I * 2);
    A.a_f = (float*)alloc(NI * 4);
    A.p_f = (float*)alloc(NU * 4);
    A.b_f = (float*)alloc(NU * 4);
    A.q_f = (float*)alloc(NI * 4);
    A.dv_u = (float*)alloc(NU * 4);
    A.de1sq_u = (float*)alloc(NI * 4);
    A.de2sq_u = (float*)alloc(NI * 4);
    A.dv_i = (float*)alloc(NI * 4);
    A.de1sq_i = (float*)alloc(NU * 4);
    A.de2sq_i = (float*)alloc(NU * 4);
    A.Xu = (float*)alloc((size_t)NU * DE * 4);
    A.Xi = (float*)alloc((size_t)NI * DE * 4);
    A.Xsu = (float*)alloc((size_t)NU * DE * 4);
    A.Xsi = (float*)alloc((size_t)NI * DE * 4);
    A.T1u = (float*)alloc((size_t)NI * DE * 4);
    A.TAu = (float*)alloc((size_t)NU * DE * 4);
    A.TBu = (float*)alloc((size_t)NI * DE * 4);
    A.T1i = (float*)alloc((size_t)NU * DE * 4);
    A.TAi = (float*)alloc((size_t)NI * DE * 4);
    A.TBi = (float*)alloc((size_t)NU * DE * 4);
    A.outp = d_out;
    (void)ws_size; (void)n_in; (void)in_sizes; (void)out_size;

    init_k<<<(NU + NI) / 256, 256, 0, stream>>>(A.cnt_u, A.cnt_i, A.flag, A.bar);
    fused<<<NBLK, NTHR, 0, stream>>>(A);
}

// Round 3
// 1284.237 us; speedup vs baseline: 1.8230x; 1.8230x over previous
//
#include <hip/hip_runtime.h>
#include <hip/hip_bf16.h>

#define NU 8192
#define NI 4096
#define DE 64
#define ELL_U 80
#define ELL_I 112
#define EPSF 1e-7f

#define NBLK 1024
#define NTHR 256
#define TOTTHR (NBLK * NTHR) /* 262144 threads, 4096 waves */
#define NWAVE (TOTTHR / 64)
#define NXCD 8

typedef unsigned short u16;
typedef unsigned int u32;

__device__ __forceinline__ float b2f(__hip_bfloat16 x) { return __bfloat162float(x); }

struct FArgs {
    const void* Hp; const void* ue; const void* ie;
    const void* w0; const void* b0; const void* w1; const void* b1;
    int* flag; int* bar; int* cnt_u; int* cnt_i; u16* idx_u; u16* idx_i;
    float* a_f; float* p_f; float* b_f; float* q_f;
    float* dv_u; float* de1sq_u; float* de2sq_u;
    float* dv_i; float* de1sq_i; float* de2sq_i;
    float* Xu; float* Xi; float* Xsu; float* Xsi;
    float* T1u; float* TAu; float* TBu;
    float* T1i; float* TAi; float* TBi;
    void* outp;
};

struct Job {
    const int* cnt; const u16* idx; int ell; int nrows;
    const float* src; float* dst; const float* evec; const float* aux;
    const float* xin; const float* dvv; float* xnext; float* xsout;
    size_t obase; int coloff;
};

// ---- grid barrier v3: per-XCD elected L2 flush ----
// bar layout (ints): [0]=arrive, [32]=flush_done, [64 + x*32]=xcd ticket x.
// Release: global arrive (relaxed RMW) -> all stores are in their XCD L2s
// (syncthreads drained vmcnt). ONE elected wave per XCD (CAS on ticket) does
// fence(RELEASE,agent) = buffer_wbl2 (flushes that whole XCD L2), bumps
// flush_done. Acquire: spin for 8 flushes, then per-block fence(ACQUIRE,agent)
// = buffer_inv (no writeback) so no stale L1/L2 lines are read.
__device__ __forceinline__ void gbar(int* bar, int& ep) {
    __syncthreads();
    ep += 1;
    if (threadIdx.x == 0) {
        __hip_atomic_fetch_add(&bar[0], 1, __ATOMIC_RELAXED, __HIP_MEMORY_SCOPE_AGENT);
        while (__hip_atomic_load(&bar[0], __ATOMIC_RELAXED, __HIP_MEMORY_SCOPE_AGENT) <
               ep * NBLK)
            __builtin_amdgcn_s_sleep(8);
        unsigned xcd;
        asm volatile("s_getreg_b32 %0, hwreg(HW_REG_XCC_ID)" : "=s"(xcd));
        int expected = ep - 1;
        if (__hip_atomic_compare_exchange_strong(&bar[64 + (xcd & 7) * 32], &expected, ep,
                                                 __ATOMIC_RELAXED, __ATOMIC_RELAXED,
                                                 __HIP_MEMORY_SCOPE_AGENT)) {
            __builtin_amdgcn_fence(__ATOMIC_RELEASE, "agent");  // wbl2 this XCD's L2
            __hip_atomic_fetch_add(&bar[32], 1, __ATOMIC_RELAXED, __HIP_MEMORY_SCOPE_AGENT);
        }
        while (__hip_atomic_load(&bar[32], __ATOMIC_RELAXED, __HIP_MEMORY_SCOPE_AGENT) <
               ep * NXCD)
            __builtin_amdgcn_s_sleep(2);
        __builtin_amdgcn_fence(__ATOMIC_ACQUIRE, "agent");  // inv (no writeback)
    }
    __syncthreads();
}

// scalar per-thread SpMV row (int or float source)
__device__ __forceinline__ float spmv_row(int n, const u16* __restrict__ ip,
                                          const void* __restrict__ s, int isint) {
    float a0 = 0.f, a1 = 0.f, a2 = 0.f, a3 = 0.f;
    int p = 0;
    if (isint) {
        const int* sv = (const int*)s;
        for (; p + 4 <= n; p += 4) {
            ushort4 cc = *(const ushort4*)(ip + p);
            a0 += (float)sv[cc.x]; a1 += (float)sv[cc.y];
            a2 += (float)sv[cc.z]; a3 += (float)sv[cc.w];
        }
        for (; p < n; p++) a0 += (float)sv[ip[p]];
    } else {
        const float* sv = (const float*)s;
        for (; p + 4 <= n; p += 4) {
            ushort4 cc = *(const ushort4*)(ip + p);
            a0 += sv[cc.x]; a1 += sv[cc.y]; a2 += sv[cc.z]; a3 += sv[cc.w];
        }
        for (; p < n; p++) a0 += sv[ip[p]];
    }
    return (a0 + a1) + (a2 + a3);
}

// one wave gathers/accumulates one 64-col row; 8 loads in flight
__device__ __forceinline__ float gather_row(int n, const u16* __restrict__ ip,
                                            const float* __restrict__ src, int lane) {
    float a0 = 0.f, a1 = 0.f, a2 = 0.f, a3 = 0.f;
    float a4 = 0.f, a5 = 0.f, a6 = 0.f, a7 = 0.f;
    int p = 0;
    if (n >= 8) {
        ushort4 cA = *(const ushort4*)(ip);
        ushort4 cB = *(const ushort4*)(ip + 4);
        while (p + 8 <= n) {
            float g0 = src[((size_t)cA.x << 6) + lane];
            float g1 = src[((size_t)cA.y << 6) + lane];
            float g2 = src[((size_t)cA.z << 6) + lane];
            float g3 = src[((size_t)cA.w << 6) + lane];
            float g4 = src[((size_t)cB.x << 6) + lane];
            float g5 = src[((size_t)cB.y << 6) + lane];
            float g6 = src[((size_t)cB.z << 6) + lane];
            float g7 = src[((size_t)cB.w << 6) + lane];
            p += 8;
            // prefetch next batch's indices (overreads <=16B into row padding)
            cA = *(const ushort4*)(ip + p);
            cB = *(const ushort4*)(ip + p + 4);
            a0 += g0; a1 += g1; a2 += g2; a3 += g3;
            a4 += g4; a5 += g5; a6 += g6; a7 += g7;
        }
    }
    if (p + 4 <= n) {
        ushort4 cc = *(const ushort4*)(ip + p);
        a0 += src[((size_t)cc.x << 6) + lane];
        a1 += src[((size_t)cc.y << 6) + lane];
        a2 += src[((size_t)cc.z << 6) + lane];
        a3 += src[((size_t)cc.w << 6) + lane];
        p += 4;
    }
    for (; p < n; p++) a4 += src[((size_t)ip[p] << 6) + lane];
    return ((a0 + a1) + (a2 + a3)) + ((a4 + a5) + (a6 + a7));
}

// one SpMM phase over both channels; waves grid-stride the 12288 rows
__device__ __forceinline__ void spmm_phase(const Job& j0, const Job& j1, int mode,
                                           const void* w, const void* bias, void* outp,
                                           int isbf, int gwave, int lane) {
    int ntot = j0.nrows + j1.nrows;
    for (int rr = gwave; rr < ntot; rr += NWAVE) {
        bool first = rr < j0.nrows;
        const Job& J = first ? j0 : j1;
        int row = first ? rr : rr - j0.nrows;
        int n = min(J.cnt[row], J.ell);
        const u16* ip = J.idx + (size_t)row * J.ell;
        float acc = gather_row(n, ip, J.src, lane);
        size_t o = ((size_t)row << 6) + lane;
        if (mode == 0) {
            J.dst[o] = acc;
        } else if (mode == 1) {
            J.dst[o] = J.evec[row] * acc;
        } else if (mode == 2) {
            J.dst[o] = acc + J.evec[row] * J.aux[o];
        } else {
            // M = dv*acc + X ; Xnext = M @ w + b ; emit output in detected dtype
            float dvr = J.dvv[row];
            float m = dvr * acc + J.xin[o];
            float x0, x1 = 0.f, x2 = 0.f, x3 = 0.f;
            if (isbf) {
                const __hip_bfloat16* __restrict__ wp = (const __hip_bfloat16*)w;
                x0 = b2f(((const __hip_bfloat16*)bias)[lane]);
                for (int k = 0; k < 64; k += 4) {
                    x0 = fmaf(__shfl(m, k, 64), b2f(wp[(k << 6) + lane]), x0);
                    x1 = fmaf(__shfl(m, k + 1, 64), b2f(wp[((k + 1) << 6) + lane]), x1);
                    x2 = fmaf(__shfl(m, k + 2, 64), b2f(wp[((k + 2) << 6) + lane]), x2);
                    x3 = fmaf(__shfl(m, k + 3, 64), b2f(wp[((k + 3) << 6) + lane]), x3);
                }
            } else {
                const float* __restrict__ wp = (const float*)w;
                x0 = ((const float*)bias)[lane];
                for (int k = 0; k < 64; k += 4) {
                    x0 = fmaf(__shfl(m, k, 64), wp[(k << 6) + lane], x0);
                    x1 = fmaf(__shfl(m, k + 1, 64), wp[((k + 1) << 6) + lane], x1);
                    x2 = fmaf(__shfl(m, k + 2, 64), wp[((k + 2) << 6) + lane], x2);
                    x3 = fmaf(__shfl(m, k + 3, 64), wp[((k + 3) << 6) + lane], x3);
                }
            }
            float xn = (x0 + x1) + (x2 + x3);
            J.xnext[o] = xn;
            J.xsout[o] = dvr * xn; // dv-premultiplied for next layer's s1
            size_t oo = J.obase + (size_t)row * 192 + J.coloff + lane;
            if (isbf) ((__hip_bfloat16*)outp)[oo] = __float2bfloat16(xn);
            else ((float*)outp)[oo] = xn;
        }
    }
}

__device__ __forceinline__ Job mkjob(const int* cnt, const u16* idx, int ell, int nrows,
                                     const float* src, float* dst, const float* evec,
                                     const float* aux, const float* xin, const float* dvv,
                                     float* xnext, float* xsout, size_t obase, int coloff) {
    Job J;
    J.cnt = cnt; J.idx = idx; J.ell = ell; J.nrows = nrows;
    J.src = src; J.dst = dst; J.evec = evec; J.aux = aux;
    J.xin = xin; J.dvv = dvv; J.xnext = xnext; J.xsout = xsout;
    J.obase = obase; J.coloff = coloff;
    return J;
}

// ---------------- init: zero counters / flag / barrier ----------------

__global__ __launch_bounds__(256) void init_k(int* cnt_u, int* cnt_i, int* flag, int* bar) {
    int t = blockIdx.x * 256 + threadIdx.x;
    if (t == 0) flag[0] = 0;
    if (t < 512) bar[t] = 0;
    if (t < NU) cnt_u[t] = 0;
    int s = t - NU;
    if (s >= 0 && s < NI) cnt_i[s] = 0;
}

// dtype probe: H values are exactly 0.0/1.0. fp32 words are 0x00000000/0x3F800000
// (low u16 always 0). bf16 pairs expose 0x3F80 in the low u16 for even-col nnz.
__global__ __launch_bounds__(256) void detect_dtype(const u32* __restrict__ Hw, int* flag) {
    int t = blockIdx.x * 256 + threadIdx.x;  // 131072 threads
    u32 w = Hw[t];
    if ((w & 0xFFFFu) == 0x3F80u) flag[0] = 1;  // benign same-value race
}

// ---------------- the single fused kernel (self-barriered) ----------------

__global__ __launch_bounds__(NTHR, 4) void fused(FArgs A) {
    const int tid = blockIdx.x * NTHR + threadIdx.x;
    const int lane = threadIdx.x & 63;
    const int gwave = tid >> 6;
    int ep = 0;
    const int isbf = A.flag[0];  // written by detect_dtype (prior dispatch)

    // ---- P2: fill ELL lists for H and H^T (grid-stride, 8 elems/thread/iter) ----
    for (int t = tid; t < NU * NI / 8; t += TOTTHR) {
        int flat = t << 3;
        int i = flat >> 12;    // user row
        int j0 = flat & 4095;  // col base
        u32 words[8];
        if (isbf) {
            uint4 v = ((const uint4*)A.Hp)[t];
            u32 p4[4] = {v.x, v.y, v.z, v.w};
#pragma unroll
            for (int q = 0; q < 4; q++) {
                words[2 * q] = p4[q] & 0xFFFFu;
                words[2 * q + 1] = p4[q] >> 16;
            }
        } else {
            uint4 a = ((const uint4*)A.Hp)[2 * t];
            uint4 b = ((const uint4*)A.Hp)[2 * t + 1];
            words[0] = a.x; words[1] = a.y; words[2] = a.z; words[3] = a.w;
            words[4] = b.x; words[5] = b.y; words[6] = b.z; words[7] = b.w;
        }
#pragma unroll
        for (int e = 0; e < 8; e++) {
            if (words[e]) {
                int j = j0 + e;
                int pu = atomicAdd(&A.cnt_u[i], 1);
                if (pu < ELL_U) A.idx_u[i * ELL_U + pu] = (u16)j;
                int pi = atomicAdd(&A.cnt_i[j], 1);
                if (pi < ELL_I) A.idx_i[j * ELL_I + pi] = (u16)i;
            }
        }
    }
    gbar(A.bar, ep);

    // ---- P3: a = H^T r (item rows, int src), p = H c (user rows, int src) ----
    if (tid < NI) {
        int n = min(A.cnt_i[tid], ELL_I);
        A.a_f[tid] = spmv_row(n, A.idx_i + (size_t)tid * ELL_I, A.cnt_u, 1);
    } else {
        int r = tid - NI;
        if (r < NU) {
            int n = min(A.cnt_u[r], ELL_U);
            A.p_f[r] = spmv_row(n, A.idx_u + (size_t)r * ELL_U, A.cnt_i, 1);
        }
    }
    gbar(A.bar, ep);

    // ---- P4: b = H a (user rows), q = H^T p (item rows) ----
    if (tid < NU) {
        int n = min(A.cnt_u[tid], ELL_U);
        A.b_f[tid] = spmv_row(n, A.idx_u + (size_t)tid * ELL_U, A.a_f, 0);
    } else {
        int r = tid - NU;
        if (r < NI) {
            int n = min(A.cnt_i[r], ELL_I);
            A.q_f[r] = spmv_row(n, A.idx_i + (size_t)r * ELL_I, A.p_f, 0);
        }
    }
    gbar(A.bar, ep);

    // ---- P5: degree vectors + fp32 working copies + layer-0 output cols ----
    if (tid < NU) {
        float r = (float)A.cnt_u[tid];
        A.dv_u[tid] = 1.0f / sqrtf(r + A.b_f[tid] + EPSF);
        A.de1sq_i[tid] = 1.0f / (r + EPSF);
        A.de2sq_i[tid] = 1.0f / (A.b_f[tid] + EPSF);
    }
    if (tid < NI) {
        float cdeg = (float)A.cnt_i[tid];
        A.dv_i[tid] = 1.0f / sqrtf(cdeg + A.q_f[tid] + EPSF);
        A.de1sq_u[tid] = 1.0f / (cdeg + EPSF);
        A.de2sq_u[tid] = 1.0f / (A.q_f[tid] + EPSF);
    }
    for (int t = tid; t < (NU + NI) * DE; t += TOTTHR) {
        if (t < NU * DE) {
            int i = t >> 6, l = t & 63;
            float v = isbf ? b2f(((const __hip_bfloat16*)A.ue)[t]) : ((const float*)A.ue)[t];
            A.Xu[t] = v;
            float dv = 1.0f / sqrtf((float)A.cnt_u[i] + A.b_f[i] + EPSF);
            A.Xsu[t] = dv * v;
            size_t o = (size_t)i * 192 + l;
            if (isbf) ((__hip_bfloat16*)A.outp)[o] = __float2bfloat16(v);
            else ((float*)A.outp)[o] = v;
        } else {
            int s = t - NU * DE;
            int i = s >> 6, l = s & 63;
            float v = isbf ? b2f(((const __hip_bfloat16*)A.ie)[s]) : ((const float*)A.ie)[s];
            A.Xi[s] = v;
            float dv = 1.0f / sqrtf((float)A.cnt_i[i] + A.q_f[i] + EPSF);
            A.Xsi[s] = dv * v;
            size_t o = (size_t)(NU + i) * 192 + l;
            if (isbf) ((__hip_bfloat16*)A.outp)[o] = __float2bfloat16(v);
            else ((float*)A.outp)[o] = v;
        }
    }
    gbar(A.bar, ep);

    // ---- P6..: the 12 SpMM phases (6 per layer, both channels each) ----
    for (int layer = 0; layer < 2; ++layer) {
        const void* w = layer ? A.w1 : A.w0;
        const void* bb = layer ? A.b1 : A.b0;
        int coloff = 64 + 64 * layer;

        // s1: T1 = A^T Xs
        spmm_phase(mkjob(A.cnt_i, A.idx_i, ELL_I, NI, A.Xsu, A.T1u, 0, 0, 0, 0, 0, 0, 0, 0),
                   mkjob(A.cnt_u, A.idx_u, ELL_U, NU, A.Xsi, A.T1i, 0, 0, 0, 0, 0, 0, 0, 0),
                   0, w, bb, A.outp, isbf, gwave, lane);
        gbar(A.bar, ep);
        // s2: T2 = A T1
        spmm_phase(mkjob(A.cnt_u, A.idx_u, ELL_U, NU, A.T1u, A.TAu, 0, 0, 0, 0, 0, 0, 0, 0),
                   mkjob(A.cnt_i, A.idx_i, ELL_I, NI, A.T1i, A.TAi, 0, 0, 0, 0, 0, 0, 0, 0),
                   0, w, bb, A.outp, isbf, gwave, lane);
        gbar(A.bar, ep);
        // s3: T3s = de2sq o (A^T T2)
        spmm_phase(mkjob(A.cnt_i, A.idx_i, ELL_I, NI, A.TAu, A.TBu, A.de2sq_u, 0, 0, 0, 0, 0, 0, 0),
                   mkjob(A.cnt_u, A.idx_u, ELL_U, NU, A.TAi, A.TBi, A.de2sq_i, 0, 0, 0, 0, 0, 0, 0),
                   1, w, bb, A.outp, isbf, gwave, lane);
        gbar(A.bar, ep);
        // s4: T4 = A T3s
        spmm_phase(mkjob(A.cnt_u, A.idx_u, ELL_U, NU, A.TBu, A.TAu, 0, 0, 0, 0, 0, 0, 0, 0),
                   mkjob(A.cnt_i, A.idx_i, ELL_I, NI, A.TBi, A.TAi, 0, 0, 0, 0, 0, 0, 0, 0),
                   0, w, bb, A.outp, isbf, gwave, lane);
        gbar(A.bar, ep);
        // s5: S = A^T T4 + de1sq o T1
        spmm_phase(mkjob(A.cnt_i, A.idx_i, ELL_I, NI, A.TAu, A.TBu, A.de1sq_u, A.T1u, 0, 0, 0, 0, 0, 0),
                   mkjob(A.cnt_u, A.idx_u, ELL_U, NU, A.TAi, A.TBi, A.de1sq_i, A.T1i, 0, 0, 0, 0, 0, 0),
                   2, w, bb, A.outp, isbf, gwave, lane);
        gbar(A.bar, ep);
        // s6: M = dv o (A S) + X ; Xnext = M w + b ; Xs = dv o Xnext ; emit output
        spmm_phase(mkjob(A.cnt_u, A.idx_u, ELL_U, NU, A.TBu, 0, 0, 0, A.Xu, A.dv_u, A.Xu, A.Xsu,
                         0, coloff),
                   mkjob(A.cnt_i, A.idx_i, ELL_I, NI, A.TBi, 0, 0, 0, A.Xi, A.dv_i, A.Xi, A.Xsi,
                         (size_t)NU * 192, coloff),
                   3, w, bb, A.outp, isbf, gwave, lane);
        if (layer == 0) gbar(A.bar, ep);  // Xsu/Xsi feed next layer's s1
    }
}

// ---------------- host ----------------

extern "C" void kernel_launch(void* const* d_in, const int* in_sizes, int n_in,
                              void* d_out, int out_size, void* d_ws, size_t ws_size,
                              hipStream_t stream) {
    char* ws = (char*)d_ws;
    size_t off = 0;
    auto alloc = [&](size_t bytes) -> char* {
        char* p = ws + off;
        off = (off + bytes + 255) & ~(size_t)255;
        return p;
    };

    FArgs A;
    A.Hp = d_in[0];
    A.ue = d_in[1];
    A.ie = d_in[2];
    A.w0 = d_in[3];
    A.b0 = d_in[4];
    A.w1 = d_in[5];
    A.b1 = d_in[6];

    A.flag = (int*)alloc(256);
    A.bar = (int*)alloc(2048);
    A.cnt_u = (int*)alloc(NU * 4);
    A.cnt_i = (int*)alloc(NI * 4);
    A.idx_u = (u16*)alloc((size_t)NU * ELL_U * 2);
    A.idx_i = (u16*)alloc((size_t)NI * ELL_I * 2);
    A.a_f = (float*)alloc(NI * 4);
    A.p_f = (float*)alloc(NU * 4);
    A.b_f = (float*)alloc(NU * 4);
    A.q_f = (float*)alloc(NI * 4);
    A.dv_u = (float*)alloc(NU * 4);
    A.de1sq_u = (float*)alloc(NI * 4);
    A.de2sq_u = (float*)alloc(NI * 4);
    A.dv_i = (float*)alloc(NI * 4);
    A.de1sq_i = (float*)alloc(NU * 4);
    A.de2sq_i = (float*)alloc(NU * 4);
    A.Xu = (float*)alloc((size_t)NU * DE * 4);
    A.Xi = (float*)alloc((size_t)NI * DE * 4);
    A.Xsu = (float*)alloc((size_t)NU * DE * 4);
    A.Xsi = (float*)alloc((size_t)NI * DE * 4);
    A.T1u = (float*)alloc((size_t)NI * DE * 4);
    A.TAu = (float*)alloc((size_t)NU * DE * 4);
    A.TBu = (float*)alloc((size_t)NI * DE * 4);
    A.T1i = (float*)alloc((size_t)NU * DE * 4);
    A.TAi = (float*)alloc((size_t)NI * DE * 4);
    A.TBi = (float*)alloc((size_t)NU * DE * 4);
    A.outp = d_out;
    (void)ws_size; (void)n_in; (void)in_sizes; (void)out_size;

    init_k<<<(NU + NI) / 256, 256, 0, stream>>>(A.cnt_u, A.cnt_i, A.flag, A.bar);
    detect_dtype<<<131072 / 256, 256, 0, stream>>>((const u32*)A.Hp, A.flag);
    fused<<<NBLK, NTHR, 0, stream>>>(A);
}

// Round 5
// 1249.645 us; speedup vs baseline: 1.8735x; 1.0277x over previous
//
#include <hip/hip_runtime.h>
#include <hip/hip_bf16.h>

#define NU 8192
#define NI 4096
#define DE 64
#define ELL_U 80
#define ELL_I 112
#define EPSF 1e-7f

#define NBLK 1024
#define NTHR 256
#define TOTTHR (NBLK * NTHR) /* 262144 threads, 4096 waves */
#define NWAVE (TOTTHR / 64)
#define NXCD 8

typedef unsigned short u16;
typedef unsigned int u32;

__device__ __forceinline__ float b2f(__hip_bfloat16 x) { return __bfloat162float(x); }

struct FArgs {
    const void* Hp; const void* ue; const void* ie;
    const void* w0; const void* b0; const void* w1; const void* b1;
    int* flag; int* bar; int* cnt_u; int* cnt_i; u16* idx_u; u16* idx_i;
    float* a_f; float* p_f; float* b_f; float* q_f;
    float* dv_u; float* de1sq_u; float* de2sq_u;
    float* dv_i; float* de1sq_i; float* de2sq_i;
    float* Xu; float* Xi; float* Xsu; float* Xsi;
    float* T1u; float* TAu; float* TBu;
    float* T1i; float* TAi; float* TBi;
    void* outp;
};

struct Job {
    const int* cnt; const u16* idx; int ell; int nrows;
    const float* src; float* dst; const float* evec; const float* aux;
    const float* xin; const float* dvv; float* xnext; float* xsout;
    size_t obase; int coloff;
};

// ---- grid barrier v5: all L2 maintenance elected per-XCD; per-block L1-only ----
// Cost model from r2/r3: ~0.5us per serialized L2 cache-maintenance command.
// r3 issued 1032/barrier (65us); v5 issues 16 (8 wbl2 + 8 inv) + per-CU L1 inv.
// bar layout (ints): [0]=arrive, [8]=flush_done, [16]=inv_done,
//                    [32+x*8]=flush ticket xcd x, [96+x*8]=inv ticket xcd x.
// Sequencing: (1) all blocks arrive (their stores are in their XCD L2s: the
// __syncthreads vmcnt-drain acked them). (2) one elected wave per XCD does
// buffer_wbl2 sc1 (write back whole L2 to the coherent LLC), bumps flush_done.
// (3) after ALL 8 flushes, one elected wave per XCD does buffer_inv sc1 (drop
// now-clean L2 so next miss refetches fresh LLC data), bumps inv_done. (4) every
// block does buffer_inv sc0 = CU-local L1 flash invalidate (parallel, ~free).
// Spin polls are device-scope atomics -> served at LLC, unaffected by L2 inv.
__device__ __forceinline__ void gbar(int* bar, int& ep) {
    __syncthreads();
    ep += 1;
    if (threadIdx.x == 0) {
        __hip_atomic_fetch_add(&bar[0], 1, __ATOMIC_RELAXED, __HIP_MEMORY_SCOPE_AGENT);
        while (__hip_atomic_load(&bar[0], __ATOMIC_RELAXED, __HIP_MEMORY_SCOPE_AGENT) <
               ep * NBLK)
            __builtin_amdgcn_s_sleep(2);
        unsigned xcd;
        asm volatile("s_getreg_b32 %0, hwreg(HW_REG_XCC_ID)" : "=s"(xcd));
        xcd &= 7;
        int exp1 = ep - 1;
        if (__hip_atomic_compare_exchange_strong(&bar[32 + xcd * 8], &exp1, ep,
                                                 __ATOMIC_RELAXED, __ATOMIC_RELAXED,
                                                 __HIP_MEMORY_SCOPE_AGENT)) {
            asm volatile("buffer_wbl2 sc1\n\ts_waitcnt vmcnt(0)" ::: "memory");
            __hip_atomic_fetch_add(&bar[8], 1, __ATOMIC_RELAXED, __HIP_MEMORY_SCOPE_AGENT);
        }
        while (__hip_atomic_load(&bar[8], __ATOMIC_RELAXED, __HIP_MEMORY_SCOPE_AGENT) <
               ep * NXCD)
            __builtin_amdgcn_s_sleep(2);
        int exp2 = ep - 1;
        if (__hip_atomic_compare_exchange_strong(&bar[96 + xcd * 8], &exp2, ep,
                                                 __ATOMIC_RELAXED, __ATOMIC_RELAXED,
                                                 __HIP_MEMORY_SCOPE_AGENT)) {
            asm volatile("buffer_inv sc1" ::: "memory");
            __hip_atomic_fetch_add(&bar[16], 1, __ATOMIC_RELAXED, __HIP_MEMORY_SCOPE_AGENT);
        }
        while (__hip_atomic_load(&bar[16], __ATOMIC_RELAXED, __HIP_MEMORY_SCOPE_AGENT) <
               ep * NXCD)
            __builtin_amdgcn_s_sleep(2);
    }
    asm volatile("buffer_inv sc0" ::: "memory");  // CU-local L1 invalidate
    __syncthreads();
}

// scalar per-thread SpMV row (int or float source)
__device__ __forceinline__ float spmv_row(int n, const u16* __restrict__ ip,
                                          const void* __restrict__ s, int isint) {
    float a0 = 0.f, a1 = 0.f, a2 = 0.f, a3 = 0.f;
    int p = 0;
    if (isint) {
        const int* sv = (const int*)s;
        for (; p + 4 <= n; p += 4) {
            ushort4 cc = *(const ushort4*)(ip + p);
            a0 += (float)sv[cc.x]; a1 += (float)sv[cc.y];
            a2 += (float)sv[cc.z]; a3 += (float)sv[cc.w];
        }
        for (; p < n; p++) a0 += (float)sv[ip[p]];
    } else {
        const float* sv = (const float*)s;
        for (; p + 4 <= n; p += 4) {
            ushort4 cc = *(const ushort4*)(ip + p);
            a0 += sv[cc.x]; a1 += sv[cc.y]; a2 += sv[cc.z]; a3 += sv[cc.w];
        }
        for (; p < n; p++) a0 += sv[ip[p]];
    }
    return (a0 + a1) + (a2 + a3);
}

// one wave gathers/accumulates one 64-col row; 8 loads in flight
__device__ __forceinline__ float gather_row(int n, const u16* __restrict__ ip,
                                            const float* __restrict__ src, int lane) {
    float a0 = 0.f, a1 = 0.f, a2 = 0.f, a3 = 0.f;
    float a4 = 0.f, a5 = 0.f, a6 = 0.f, a7 = 0.f;
    int p = 0;
    if (n >= 8) {
        ushort4 cA = *(const ushort4*)(ip);
        ushort4 cB = *(const ushort4*)(ip + 4);
        while (p + 8 <= n) {
            float g0 = src[((size_t)cA.x << 6) + lane];
            float g1 = src[((size_t)cA.y << 6) + lane];
            float g2 = src[((size_t)cA.z << 6) + lane];
            float g3 = src[((size_t)cA.w << 6) + lane];
            float g4 = src[((size_t)cB.x << 6) + lane];
            float g5 = src[((size_t)cB.y << 6) + lane];
            float g6 = src[((size_t)cB.z << 6) + lane];
            float g7 = src[((size_t)cB.w << 6) + lane];
            p += 8;
            // prefetch next batch's indices (overreads <=16B into row padding)
            cA = *(const ushort4*)(ip + p);
            cB = *(const ushort4*)(ip + p + 4);
            a0 += g0; a1 += g1; a2 += g2; a3 += g3;
            a4 += g4; a5 += g5; a6 += g6; a7 += g7;
        }
    }
    if (p + 4 <= n) {
        ushort4 cc = *(const ushort4*)(ip + p);
        a0 += src[((size_t)cc.x << 6) + lane];
        a1 += src[((size_t)cc.y << 6) + lane];
        a2 += src[((size_t)cc.z << 6) + lane];
        a3 += src[((size_t)cc.w << 6) + lane];
        p += 4;
    }
    for (; p < n; p++) a4 += src[((size_t)ip[p] << 6) + lane];
    return ((a0 + a1) + (a2 + a3)) + ((a4 + a5) + (a6 + a7));
}

// one SpMM phase over both channels; waves grid-stride the 12288 rows
__device__ __forceinline__ void spmm_phase(const Job& j0, const Job& j1, int mode,
                                           const void* w, const void* bias, void* outp,
                                           int isbf, int gwave, int lane) {
    int ntot = j0.nrows + j1.nrows;
    for (int rr = gwave; rr < ntot; rr += NWAVE) {
        bool first = rr < j0.nrows;
        const Job& J = first ? j0 : j1;
        int row = first ? rr : rr - j0.nrows;
        int n = min(J.cnt[row], J.ell);
        const u16* ip = J.idx + (size_t)row * J.ell;
        float acc = gather_row(n, ip, J.src, lane);
        size_t o = ((size_t)row << 6) + lane;
        if (mode == 0) {
            J.dst[o] = acc;
        } else if (mode == 1) {
            J.dst[o] = J.evec[row] * acc;
        } else if (mode == 2) {
            J.dst[o] = acc + J.evec[row] * J.aux[o];
        } else {
            // M = dv*acc + X ; Xnext = M @ w + b ; emit output in detected dtype
            float dvr = J.dvv[row];
            float m = dvr * acc + J.xin[o];
            float x0, x1 = 0.f, x2 = 0.f, x3 = 0.f;
            if (isbf) {
                const __hip_bfloat16* __restrict__ wp = (const __hip_bfloat16*)w;
                x0 = b2f(((const __hip_bfloat16*)bias)[lane]);
                for (int k = 0; k < 64; k += 4) {
                    x0 = fmaf(__shfl(m, k, 64), b2f(wp[(k << 6) + lane]), x0);
                    x1 = fmaf(__shfl(m, k + 1, 64), b2f(wp[((k + 1) << 6) + lane]), x1);
                    x2 = fmaf(__shfl(m, k + 2, 64), b2f(wp[((k + 2) << 6) + lane]), x2);
                    x3 = fmaf(__shfl(m, k + 3, 64), b2f(wp[((k + 3) << 6) + lane]), x3);
                }
            } else {
                const float* __restrict__ wp = (const float*)w;
                x0 = ((const float*)bias)[lane];
                for (int k = 0; k < 64; k += 4) {
                    x0 = fmaf(__shfl(m, k, 64), wp[(k << 6) + lane], x0);
                    x1 = fmaf(__shfl(m, k + 1, 64), wp[((k + 1) << 6) + lane], x1);
                    x2 = fmaf(__shfl(m, k + 2, 64), wp[((k + 2) << 6) + lane], x2);
                    x3 = fmaf(__shfl(m, k + 3, 64), wp[((k + 3) << 6) + lane], x3);
                }
            }
            float xn = (x0 + x1) + (x2 + x3);
            J.xnext[o] = xn;
            J.xsout[o] = dvr * xn; // dv-premultiplied for next layer's s1
            size_t oo = J.obase + (size_t)row * 192 + J.coloff + lane;
            if (isbf) ((__hip_bfloat16*)outp)[oo] = __float2bfloat16(xn);
            else ((float*)outp)[oo] = xn;
        }
    }
}

__device__ __forceinline__ Job mkjob(const int* cnt, const u16* idx, int ell, int nrows,
                                     const float* src, float* dst, const float* evec,
                                     const float* aux, const float* xin, const float* dvv,
                                     float* xnext, float* xsout, size_t obase, int coloff) {
    Job J;
    J.cnt = cnt; J.idx = idx; J.ell = ell; J.nrows = nrows;
    J.src = src; J.dst = dst; J.evec = evec; J.aux = aux;
    J.xin = xin; J.dvv = dvv; J.xnext = xnext; J.xsout = xsout;
    J.obase = obase; J.coloff = coloff;
    return J;
}

// ---------------- init: zero counters / flag / barrier ----------------

__global__ __launch_bounds__(256) void init_k(int* cnt_u, int* cnt_i, int* flag, int* bar) {
    int t = blockIdx.x * 256 + threadIdx.x;
    if (t == 0) flag[0] = 0;
    if (t < 512) bar[t] = 0;
    if (t < NU) cnt_u[t] = 0;
    int s = t - NU;
    if (s >= 0 && s < NI) cnt_i[s] = 0;
}

// dtype probe: H values are exactly 0.0/1.0. fp32 words are 0x00000000/0x3F800000
// (low u16 always 0). bf16 pairs expose 0x3F80 in the low u16 for even-col nnz.
__global__ __launch_bounds__(256) void detect_dtype(const u32* __restrict__ Hw, int* flag) {
    int t = blockIdx.x * 256 + threadIdx.x;  // 131072 threads
    u32 w = Hw[t];
    if ((w & 0xFFFFu) == 0x3F80u) flag[0] = 1;  // benign same-value race
}

// ---------------- the single fused kernel (self-barriered) ----------------

__global__ __launch_bounds__(NTHR, 4) void fused(FArgs A) {
    const int tid = blockIdx.x * NTHR + threadIdx.x;
    const int lane = threadIdx.x & 63;
    const int gwave = tid >> 6;
    int ep = 0;
    const int isbf = A.flag[0];  // written by detect_dtype (prior dispatch)

    // ---- P2: fill ELL lists for H and H^T (grid-stride, 8 elems/thread/iter) ----
    for (int t = tid; t < NU * NI / 8; t += TOTTHR) {
        int flat = t << 3;
        int i = flat >> 12;    // user row
        int j0 = flat & 4095;  // col base
        u32 words[8];
        if (isbf) {
            uint4 v = ((const uint4*)A.Hp)[t];
            u32 p4[4] = {v.x, v.y, v.z, v.w};
#pragma unroll
            for (int q = 0; q < 4; q++) {
                words[2 * q] = p4[q] & 0xFFFFu;
                words[2 * q + 1] = p4[q] >> 16;
            }
        } else {
            uint4 a = ((const uint4*)A.Hp)[2 * t];
            uint4 b = ((const uint4*)A.Hp)[2 * t + 1];
            words[0] = a.x; words[1] = a.y; words[2] = a.z; words[3] = a.w;
            words[4] = b.x; words[5] = b.y; words[6] = b.z; words[7] = b.w;
        }
#pragma unroll
        for (int e = 0; e < 8; e++) {
            if (words[e]) {
                int j = j0 + e;
                int pu = atomicAdd(&A.cnt_u[i], 1);
                if (pu < ELL_U) A.idx_u[i * ELL_U + pu] = (u16)j;
                int pi = atomicAdd(&A.cnt_i[j], 1);
                if (pi < ELL_I) A.idx_i[j * ELL_I + pi] = (u16)i;
            }
        }
    }
    gbar(A.bar, ep);

    // ---- P3: a = H^T r (item rows, int src), p = H c (user rows, int src) ----
    if (tid < NI) {
        int n = min(A.cnt_i[tid], ELL_I);
        A.a_f[tid] = spmv_row(n, A.idx_i + (size_t)tid * ELL_I, A.cnt_u, 1);
    } else {
        int r = tid - NI;
        if (r < NU) {
            int n = min(A.cnt_u[r], ELL_U);
            A.p_f[r] = spmv_row(n, A.idx_u + (size_t)r * ELL_U, A.cnt_i, 1);
        }
    }
    gbar(A.bar, ep);

    // ---- P4: b = H a (user rows), q = H^T p (item rows) ----
    if (tid < NU) {
        int n = min(A.cnt_u[tid], ELL_U);
        A.b_f[tid] = spmv_row(n, A.idx_u + (size_t)tid * ELL_U, A.a_f, 0);
    } else {
        int r = tid - NU;
        if (r < NI) {
            int n = min(A.cnt_i[r], ELL_I);
            A.q_f[r] = spmv_row(n, A.idx_i + (size_t)r * ELL_I, A.p_f, 0);
        }
    }
    gbar(A.bar, ep);

    // ---- P5: degree vectors + fp32 working copies + layer-0 output cols ----
    if (tid < NU) {
        float r = (float)A.cnt_u[tid];
        A.dv_u[tid] = 1.0f / sqrtf(r + A.b_f[tid] + EPSF);
        A.de1sq_i[tid] = 1.0f / (r + EPSF);
        A.de2sq_i[tid] = 1.0f / (A.b_f[tid] + EPSF);
    }
    if (tid < NI) {
        float cdeg = (float)A.cnt_i[tid];
        A.dv_i[tid] = 1.0f / sqrtf(cdeg + A.q_f[tid] + EPSF);
        A.de1sq_u[tid] = 1.0f / (cdeg + EPSF);
        A.de2sq_u[tid] = 1.0f / (A.q_f[tid] + EPSF);
    }
    for (int t = tid; t < (NU + NI) * DE; t += TOTTHR) {
        if (t < NU * DE) {
            int i = t >> 6, l = t & 63;
            float v = isbf ? b2f(((const __hip_bfloat16*)A.ue)[t]) : ((const float*)A.ue)[t];
            A.Xu[t] = v;
            float dv = 1.0f / sqrtf((float)A.cnt_u[i] + A.b_f[i] + EPSF);
            A.Xsu[t] = dv * v;
            size_t o = (size_t)i * 192 + l;
            if (isbf) ((__hip_bfloat16*)A.outp)[o] = __float2bfloat16(v);
            else ((float*)A.outp)[o] = v;
        } else {
            int s = t - NU * DE;
            int i = s >> 6, l = s & 63;
            float v = isbf ? b2f(((const __hip_bfloat16*)A.ie)[s]) : ((const float*)A.ie)[s];
            A.Xi[s] = v;
            float dv = 1.0f / sqrtf((float)A.cnt_i[i] + A.q_f[i] + EPSF);
            A.Xsi[s] = dv * v;
            size_t o = (size_t)(NU + i) * 192 + l;
            if (isbf) ((__hip_bfloat16*)A.outp)[o] = __float2bfloat16(v);
            else ((float*)A.outp)[o] = v;
        }
    }
    gbar(A.bar, ep);

    // ---- P6..: the 12 SpMM phases (6 per layer, both channels each) ----
    for (int layer = 0; layer < 2; ++layer) {
        const void* w = layer ? A.w1 : A.w0;
        const void* bb = layer ? A.b1 : A.b0;
        int coloff = 64 + 64 * layer;

        // s1: T1 = A^T Xs
        spmm_phase(mkjob(A.cnt_i, A.idx_i, ELL_I, NI, A.Xsu, A.T1u, 0, 0, 0, 0, 0, 0, 0, 0),
                   mkjob(A.cnt_u, A.idx_u, ELL_U, NU, A.Xsi, A.T1i, 0, 0, 0, 0, 0, 0, 0, 0),
                   0, w, bb, A.outp, isbf, gwave, lane);
        gbar(A.bar, ep);
        // s2: T2 = A T1
        spmm_phase(mkjob(A.cnt_u, A.idx_u, ELL_U, NU, A.T1u, A.TAu, 0, 0, 0, 0, 0, 0, 0, 0),
                   mkjob(A.cnt_i, A.idx_i, ELL_I, NI, A.T1i, A.TAi, 0, 0, 0, 0, 0, 0, 0, 0),
                   0, w, bb, A.outp, isbf, gwave, lane);
        gbar(A.bar, ep);
        // s3: T3s = de2sq o (A^T T2)
        spmm_phase(mkjob(A.cnt_i, A.idx_i, ELL_I, NI, A.TAu, A.TBu, A.de2sq_u, 0, 0, 0, 0, 0, 0, 0),
                   mkjob(A.cnt_u, A.idx_u, ELL_U, NU, A.TAi, A.TBi, A.de2sq_i, 0, 0, 0, 0, 0, 0, 0),
                   1, w, bb, A.outp, isbf, gwave, lane);
        gbar(A.bar, ep);
        // s4: T4 = A T3s
        spmm_phase(mkjob(A.cnt_u, A.idx_u, ELL_U, NU, A.TBu, A.TAu, 0, 0, 0, 0, 0, 0, 0, 0),
                   mkjob(A.cnt_i, A.idx_i, ELL_I, NI, A.TBi, A.TAi, 0, 0, 0, 0, 0, 0, 0, 0),
                   0, w, bb, A.outp, isbf, gwave, lane);
        gbar(A.bar, ep);
        // s5: S = A^T T4 + de1sq o T1
        spmm_phase(mkjob(A.cnt_i, A.idx_i, ELL_I, NI, A.TAu, A.TBu, A.de1sq_u, A.T1u, 0, 0, 0, 0, 0, 0),
                   mkjob(A.cnt_u, A.idx_u, ELL_U, NU, A.TAi, A.TBi, A.de1sq_i, A.T1i, 0, 0, 0, 0, 0, 0),
                   2, w, bb, A.outp, isbf, gwave, lane);
        gbar(A.bar, ep);
        // s6: M = dv o (A S) + X ; Xnext = M w + b ; Xs = dv o Xnext ; emit output
        spmm_phase(mkjob(A.cnt_u, A.idx_u, ELL_U, NU, A.TBu, 0, 0, 0, A.Xu, A.dv_u, A.Xu, A.Xsu,
                         0, coloff),
                   mkjob(A.cnt_i, A.idx_i, ELL_I, NI, A.TBi, 0, 0, 0, A.Xi, A.dv_i, A.Xi, A.Xsi,
                         (size_t)NU * 192, coloff),
                   3, w, bb, A.outp, isbf, gwave, lane);
        if (layer == 0) gbar(A.bar, ep);  // Xsu/Xsi feed next layer's s1
    }
}

// ---------------- host ----------------

extern "C" void kernel_launch(void* const* d_in, const int* in_sizes, int n_in,
                              void* d_out, int out_size, void* d_ws, size_t ws_size,
                              hipStream_t stream) {
    char* ws = (char*)d_ws;
    size_t off = 0;
    auto alloc = [&](size_t bytes) -> char* {
        char* p = ws + off;
        off = (off + bytes + 255) & ~(size_t)255;
        return p;
    };

    FArgs A;
    A.Hp = d_in[0];
    A.ue = d_in[1];
    A.ie = d_in[2];
    A.w0 = d_in[3];
    A.b0 = d_in[4];
    A.w1 = d_in[5];
    A.b1 = d_in[6];

    A.flag = (int*)alloc(256);
    A.bar = (int*)alloc(2048);
    A.cnt_u = (int*)alloc(NU * 4);
    A.cnt_i = (int*)alloc(NI * 4);
    A.idx_u = (u16*)alloc((size_t)NU * ELL_U * 2);
    A.idx_i = (u16*)alloc((size_t)NI * ELL_I * 2);
    A.a_f = (float*)alloc(NI * 4);
    A.p_f = (float*)alloc(NU * 4);
    A.b_f = (float*)alloc(NU * 4);
    A.q_f = (float*)alloc(NI * 4);
    A.dv_u = (float*)alloc(NU * 4);
    A.de1sq_u = (float*)alloc(NI * 4);
    A.de2sq_u = (float*)alloc(NI * 4);
    A.dv_i = (float*)alloc(NI * 4);
    A.de1sq_i = (float*)alloc(NU * 4);
    A.de2sq_i = (float*)alloc(NU * 4);
    A.Xu = (float*)alloc((size_t)NU * DE * 4);
    A.Xi = (float*)alloc((size_t)NI * DE * 4);
    A.Xsu = (float*)alloc((size_t)NU * DE * 4);
    A.Xsi = (float*)alloc((size_t)NI * DE * 4);
    A.T1u = (float*)alloc((size_t)NI * DE * 4);
    A.TAu = (float*)alloc((size_t)NU * DE * 4);
    A.TBu = (float*)alloc((size_t)NI * DE * 4);
    A.T1i = (float*)alloc((size_t)NU * DE * 4);
    A.TAi = (float*)alloc((size_t)NI * DE * 4);
    A.TBi = (float*)alloc((size_t)NU * DE * 4);
    A.outp = d_out;
    (void)ws_size; (void)n_in; (void)in_sizes; (void)out_size;

    init_k<<<(NU + NI) / 256, 256, 0, stream>>>(A.cnt_u, A.cnt_i, A.flag, A.bar);
    detect_dtype<<<131072 / 256, 256, 0, stream>>>((const u32*)A.Hp, A.flag);
    fused<<<NBLK, NTHR, 0, stream>>>(A);
}

// Round 6
// 530.804 us; speedup vs baseline: 4.4107x; 2.3542x over previous
//
#include <hip/hip_runtime.h>
#include <hip/hip_bf16.h>

#define NU 8192
#define NI 4096
#define DE 64
#define ELL_U 80
#define ELL_I 112
#define EPSF 1e-7f

#define NBLK 1024
#define NTHR 256
#define TOTTHR (NBLK * NTHR) /* 262144 threads, 4096 waves */
#define NWAVE (TOTTHR / 64)
#define NGRP 32
#define GRPSZ (NBLK / NGRP) /* 32 */

typedef unsigned int u32;

__device__ __forceinline__ float b2f(__hip_bfloat16 x) { return __bfloat162float(x); }

// sc1 (agent-scope relaxed) store: write-through to the coherent LLC, no dirty
// L2 line. All cross-phase workspace writes use this; consumers use NORMAL
// cached loads, which is sound because every buffer is SSA (written once,
// before first read, never rewritten) -> a consumer's first touch misses L2
// and fetches the final value from the LLC.
template <typename T>
__device__ __forceinline__ void st_dev(T* p, T v) {
    __hip_atomic_store(p, v, __ATOMIC_RELAXED, __HIP_MEMORY_SCOPE_AGENT);
}

// ---- full-SSA workspace layout (compile-time offsets; ~53 MB of 512 MB) ----
struct WS {
    int bar[1024];                       // hierarchical barrier counters
    int cnt_u[NU]; int cnt_i[NI]; int flag; int pad[63];
    u32 idx_u[NU * ELL_U]; u32 idx_i[NI * ELL_I];
    float a_f[NI]; float p_f[NU]; float b_f[NU]; float q_f[NI];
    float dv_u[NU]; float de1sq_u[NI]; float de2sq_u[NI];
    float dv_i[NI]; float de1sq_i[NU]; float de2sq_i[NU];
    float Xu[3][NU * DE]; float Xsu[3][NU * DE];   // X generations 0,1,2
    float Xi[3][NI * DE]; float Xsi[3][NI * DE];
    float T1u[2][NI * DE]; float T2u[2][NU * DE]; float T3u[2][NI * DE];
    float T4u[2][NU * DE]; float Su[2][NI * DE];   // per-layer fresh temps (u chan)
    float T1i[2][NU * DE]; float T2i[2][NI * DE]; float T3i[2][NU * DE];
    float T4i[2][NI * DE]; float Si[2][NU * DE];   // per-layer fresh temps (i chan)
};

struct Job {
    const int* cnt; const u32* idx; int ell; int nrows;
    const float* src; float* dst; const float* evec; const float* aux;
    const float* xin; const float* dvv; float* xnext; float* xsout;
    size_t obase; int coloff;
};

// ---- grid barrier v6: pure arrival counting, ZERO cache maintenance ----
// r2/r3/r5 showed any barrier containing buffer_wbl2 costs ~60us (full 4MiB L2
// tag walk). With sc1 write-through stores + SSA buffers there is nothing to
// write back and nothing stale to invalidate, so the barrier is just counters.
// Hierarchical arrive: 32 group counters (64B apart -> parallel LLC banks,
// ~32 serialized RMWs each), last group-arriver bumps root, all spin on root.
__device__ __forceinline__ void gbar(int* bar, int& ep) {
    __threadfence_block();  // per-thread vmcnt drain: sc1 stores acked at LLC
    __syncthreads();
    ep += 1;
    if (threadIdx.x == 0) {
        int g = blockIdx.x >> 5;  // 32 groups of 32 blocks
        int prev = __hip_atomic_fetch_add(&bar[64 + g * 16], 1, __ATOMIC_RELAXED,
                                          __HIP_MEMORY_SCOPE_AGENT);
        if (prev == ep * GRPSZ - 1)  // last arriver of this group this epoch
            __hip_atomic_fetch_add(&bar[0], 1, __ATOMIC_RELAXED,
                                   __HIP_MEMORY_SCOPE_AGENT);
        while (__hip_atomic_load(&bar[0], __ATOMIC_RELAXED,
                                 __HIP_MEMORY_SCOPE_AGENT) < ep * NGRP)
            __builtin_amdgcn_s_sleep(2);
    }
    asm volatile("" ::: "memory");  // no load hoisting above the spin
    __syncthreads();
}

// scalar per-thread SpMV row (int or float source); normal cached loads
__device__ __forceinline__ float spmv_row(int n, const u32* __restrict__ ip,
                                          const void* __restrict__ s, int isint) {
    float a0 = 0.f, a1 = 0.f, a2 = 0.f, a3 = 0.f;
    int p = 0;
    if (isint) {
        const int* sv = (const int*)s;
        for (; p + 4 <= n; p += 4) {
            uint4 cc = *(const uint4*)(ip + p);
            a0 += (float)sv[cc.x]; a1 += (float)sv[cc.y];
            a2 += (float)sv[cc.z]; a3 += (float)sv[cc.w];
        }
        for (; p < n; p++) a0 += (float)sv[ip[p]];
    } else {
        const float* sv = (const float*)s;
        for (; p + 4 <= n; p += 4) {
            uint4 cc = *(const uint4*)(ip + p);
            a0 += sv[cc.x]; a1 += sv[cc.y]; a2 += sv[cc.z]; a3 += sv[cc.w];
        }
        for (; p < n; p++) a0 += sv[ip[p]];
    }
    return (a0 + a1) + (a2 + a3);
}

// one wave gathers/accumulates one 64-col row; 8 loads in flight; cached loads
__device__ __forceinline__ float gather_row(int n, const u32* __restrict__ ip,
                                            const float* __restrict__ src, int lane) {
    float a0 = 0.f, a1 = 0.f, a2 = 0.f, a3 = 0.f;
    float a4 = 0.f, a5 = 0.f, a6 = 0.f, a7 = 0.f;
    int p = 0;
    if (n >= 8) {
        uint4 cA = *(const uint4*)(ip);
        uint4 cB = *(const uint4*)(ip + 4);
        while (p + 8 <= n) {
            float g0 = src[((size_t)cA.x << 6) + lane];
            float g1 = src[((size_t)cA.y << 6) + lane];
            float g2 = src[((size_t)cA.z << 6) + lane];
            float g3 = src[((size_t)cA.w << 6) + lane];
            float g4 = src[((size_t)cB.x << 6) + lane];
            float g5 = src[((size_t)cB.y << 6) + lane];
            float g6 = src[((size_t)cB.z << 6) + lane];
            float g7 = src[((size_t)cB.w << 6) + lane];
            p += 8;
            // prefetch next batch's indices (overreads <=32B into padding/next row)
            cA = *(const uint4*)(ip + p);
            cB = *(const uint4*)(ip + p + 4);
            a0 += g0; a1 += g1; a2 += g2; a3 += g3;
            a4 += g4; a5 += g5; a6 += g6; a7 += g7;
        }
    }
    if (p + 4 <= n) {
        uint4 cc = *(const uint4*)(ip + p);
        a0 += src[((size_t)cc.x << 6) + lane];
        a1 += src[((size_t)cc.y << 6) + lane];
        a2 += src[((size_t)cc.z << 6) + lane];
        a3 += src[((size_t)cc.w << 6) + lane];
        p += 4;
    }
    for (; p < n; p++) a4 += src[((size_t)ip[p] << 6) + lane];
    return ((a0 + a1) + (a2 + a3)) + ((a4 + a5) + (a6 + a7));
}

// one SpMM phase over both channels; waves grid-stride the 12288 rows
__device__ __forceinline__ void spmm_phase(const Job& j0, const Job& j1, int mode,
                                           const void* w, const void* bias, void* outp,
                                           int isbf, int gwave, int lane) {
    int ntot = j0.nrows + j1.nrows;
    for (int rr = gwave; rr < ntot; rr += NWAVE) {
        bool first = rr < j0.nrows;
        const Job& J = first ? j0 : j1;
        int row = first ? rr : rr - j0.nrows;
        int n = min(J.cnt[row], J.ell);
        const u32* ip = J.idx + (size_t)row * J.ell;
        float acc = gather_row(n, ip, J.src, lane);
        size_t o = ((size_t)row << 6) + lane;
        if (mode == 0) {
            st_dev(J.dst + o, acc);
        } else if (mode == 1) {
            st_dev(J.dst + o, J.evec[row] * acc);
        } else if (mode == 2) {
            st_dev(J.dst + o, acc + J.evec[row] * J.aux[o]);
        } else {
            // M = dv*acc + X ; Xnext = M @ w + b ; emit output in detected dtype
            float dvr = J.dvv[row];
            float m = dvr * acc + J.xin[o];
            float x0, x1 = 0.f, x2 = 0.f, x3 = 0.f;
            if (isbf) {
                const __hip_bfloat16* __restrict__ wp = (const __hip_bfloat16*)w;
                x0 = b2f(((const __hip_bfloat16*)bias)[lane]);
                for (int k = 0; k < 64; k += 4) {
                    x0 = fmaf(__shfl(m, k, 64), b2f(wp[(k << 6) + lane]), x0);
                    x1 = fmaf(__shfl(m, k + 1, 64), b2f(wp[((k + 1) << 6) + lane]), x1);
                    x2 = fmaf(__shfl(m, k + 2, 64), b2f(wp[((k + 2) << 6) + lane]), x2);
                    x3 = fmaf(__shfl(m, k + 3, 64), b2f(wp[((k + 3) << 6) + lane]), x3);
                }
            } else {
                const float* __restrict__ wp = (const float*)w;
                x0 = ((const float*)bias)[lane];
                for (int k = 0; k < 64; k += 4) {
                    x0 = fmaf(__shfl(m, k, 64), wp[(k << 6) + lane], x0);
                    x1 = fmaf(__shfl(m, k + 1, 64), wp[((k + 1) << 6) + lane], x1);
                    x2 = fmaf(__shfl(m, k + 2, 64), wp[((k + 2) << 6) + lane], x2);
                    x3 = fmaf(__shfl(m, k + 3, 64), wp[((k + 3) << 6) + lane], x3);
                }
            }
            float xn = (x0 + x1) + (x2 + x3);
            st_dev(J.xnext + o, xn);
            st_dev(J.xsout + o, dvr * xn);  // dv-premultiplied for next layer's s1
            size_t oo = J.obase + (size_t)row * 192 + J.coloff + lane;
            if (isbf) ((__hip_bfloat16*)outp)[oo] = __float2bfloat16(xn);
            else ((float*)outp)[oo] = xn;
        }
    }
}

__device__ __forceinline__ Job mkjob(const int* cnt, const u32* idx, int ell, int nrows,
                                     const float* src, float* dst, const float* evec,
                                     const float* aux, const float* xin, const float* dvv,
                                     float* xnext, float* xsout, size_t obase, int coloff) {
    Job J;
    J.cnt = cnt; J.idx = idx; J.ell = ell; J.nrows = nrows;
    J.src = src; J.dst = dst; J.evec = evec; J.aux = aux;
    J.xin = xin; J.dvv = dvv; J.xnext = xnext; J.xsout = xsout;
    J.obase = obase; J.coloff = coloff;
    return J;
}

// ---------------- init: zero counters / flag / barrier ----------------

__global__ __launch_bounds__(256) void init_k(WS* W) {
    int t = blockIdx.x * 256 + threadIdx.x;
    if (t == 0) W->flag = 0;
    if (t < 1024) W->bar[t] = 0;
    if (t < NU) W->cnt_u[t] = 0;
    int s = t - NU;
    if (s >= 0 && s < NI) W->cnt_i[s] = 0;
}

// dtype probe: H values are exactly 0.0/1.0. fp32 words are 0x00000000/0x3F800000
// (low u16 always 0). bf16 pairs expose 0x3F80 in the low u16 for even-col nnz.
__global__ __launch_bounds__(256) void detect_dtype(const u32* __restrict__ Hw, WS* W) {
    int t = blockIdx.x * 256 + threadIdx.x;  // 131072 threads
    u32 w = Hw[t];
    if ((w & 0xFFFFu) == 0x3F80u) W->flag = 1;  // benign same-value race
}

// ---------------- the single fused kernel (self-barriered, SSA) ----------------

struct FArgs {
    const void* Hp; const void* ue; const void* ie;
    const void* w0; const void* b0; const void* w1; const void* b1;
    WS* W; void* outp;
};

__global__ __launch_bounds__(NTHR, 4) void fused(FArgs A) {
    WS* W = A.W;
    const int tid = blockIdx.x * NTHR + threadIdx.x;
    const int lane = threadIdx.x & 63;
    const int gwave = tid >> 6;
    int ep = 0;
    const int isbf = W->flag;  // written by detect_dtype (prior dispatch)

    // ---- P2: fill ELL lists for H and H^T (grid-stride, 8 elems/thread/iter) ----
    // cnt via agent atomicAdd (LLC); idx via sc1 stores.
    for (int t = tid; t < NU * NI / 8; t += TOTTHR) {
        int flat = t << 3;
        int i = flat >> 12;    // user row
        int j0 = flat & 4095;  // col base
        u32 words[8];
        if (isbf) {
            uint4 v = ((const uint4*)A.Hp)[t];
            u32 p4[4] = {v.x, v.y, v.z, v.w};
#pragma unroll
            for (int q = 0; q < 4; q++) {
                words[2 * q] = p4[q] & 0xFFFFu;
                words[2 * q + 1] = p4[q] >> 16;
            }
        } else {
            uint4 a = ((const uint4*)A.Hp)[2 * t];
            uint4 b = ((const uint4*)A.Hp)[2 * t + 1];
            words[0] = a.x; words[1] = a.y; words[2] = a.z; words[3] = a.w;
            words[4] = b.x; words[5] = b.y; words[6] = b.z; words[7] = b.w;
        }
#pragma unroll
        for (int e = 0; e < 8; e++) {
            if (words[e]) {
                int j = j0 + e;
                int pu = atomicAdd(&W->cnt_u[i], 1);
                if (pu < ELL_U) st_dev(&W->idx_u[i * ELL_U + pu], (u32)j);
                int pi = atomicAdd(&W->cnt_i[j], 1);
                if (pi < ELL_I) st_dev(&W->idx_i[j * ELL_I + pi], (u32)i);
            }
        }
    }
    gbar(W->bar, ep);

    // ---- P3: a = H^T r (item rows, int src), p = H c (user rows, int src) ----
    if (tid < NI) {
        int n = min(W->cnt_i[tid], ELL_I);
        st_dev(&W->a_f[tid], spmv_row(n, W->idx_i + (size_t)tid * ELL_I, W->cnt_u, 1));
    } else {
        int r = tid - NI;
        if (r < NU) {
            int n = min(W->cnt_u[r], ELL_U);
            st_dev(&W->p_f[r], spmv_row(n, W->idx_u + (size_t)r * ELL_U, W->cnt_i, 1));
        }
    }
    gbar(W->bar, ep);

    // ---- P4: b = H a (user rows), q = H^T p (item rows) ----
    if (tid < NU) {
        int n = min(W->cnt_u[tid], ELL_U);
        st_dev(&W->b_f[tid], spmv_row(n, W->idx_u + (size_t)tid * ELL_U, W->a_f, 0));
    } else {
        int r = tid - NU;
        if (r < NI) {
            int n = min(W->cnt_i[r], ELL_I);
            st_dev(&W->q_f[r], spmv_row(n, W->idx_i + (size_t)r * ELL_I, W->p_f, 0));
        }
    }
    gbar(W->bar, ep);

    // ---- P5: degree vectors + fp32 working copies + layer-0 output cols ----
    if (tid < NU) {
        float r = (float)W->cnt_u[tid];
        float bf_ = W->b_f[tid];
        st_dev(&W->dv_u[tid], 1.0f / sqrtf(r + bf_ + EPSF));
        st_dev(&W->de1sq_i[tid], 1.0f / (r + EPSF));
        st_dev(&W->de2sq_i[tid], 1.0f / (bf_ + EPSF));
    }
    if (tid < NI) {
        float cdeg = (float)W->cnt_i[tid];
        float qf_ = W->q_f[tid];
        st_dev(&W->dv_i[tid], 1.0f / sqrtf(cdeg + qf_ + EPSF));
        st_dev(&W->de1sq_u[tid], 1.0f / (cdeg + EPSF));
        st_dev(&W->de2sq_u[tid], 1.0f / (qf_ + EPSF));
    }
    for (int t = tid; t < (NU + NI) * DE; t += TOTTHR) {
        if (t < NU * DE) {
            int i = t >> 6, l = t & 63;
            float v = isbf ? b2f(((const __hip_bfloat16*)A.ue)[t]) : ((const float*)A.ue)[t];
            st_dev(&W->Xu[0][t], v);
            float dv = 1.0f / sqrtf((float)W->cnt_u[i] + W->b_f[i] + EPSF);
            st_dev(&W->Xsu[0][t], dv * v);
            size_t o = (size_t)i * 192 + l;
            if (isbf) ((__hip_bfloat16*)A.outp)[o] = __float2bfloat16(v);
            else ((float*)A.outp)[o] = v;
        } else {
            int s = t - NU * DE;
            int i = s >> 6, l = s & 63;
            float v = isbf ? b2f(((const __hip_bfloat16*)A.ie)[s]) : ((const float*)A.ie)[s];
            st_dev(&W->Xi[0][s], v);
            float dv = 1.0f / sqrtf((float)W->cnt_i[i] + W->q_f[i] + EPSF);
            st_dev(&W->Xsi[0][s], dv * v);
            size_t o = (size_t)(NU + i) * 192 + l;
            if (isbf) ((__hip_bfloat16*)A.outp)[o] = __float2bfloat16(v);
            else ((float*)A.outp)[o] = v;
        }
    }
    gbar(W->bar, ep);

    // ---- P6..: the 12 SpMM phases (6 per layer, both channels; all SSA) ----
    for (int layer = 0; layer < 2; ++layer) {
        const void* w = layer ? A.w1 : A.w0;
        const void* bb = layer ? A.b1 : A.b0;
        int coloff = 64 + 64 * layer;

        // s1: T1 = A^T Xs
        spmm_phase(mkjob(W->cnt_i, W->idx_i, ELL_I, NI, W->Xsu[layer], W->T1u[layer],
                         0, 0, 0, 0, 0, 0, 0, 0),
                   mkjob(W->cnt_u, W->idx_u, ELL_U, NU, W->Xsi[layer], W->T1i[layer],
                         0, 0, 0, 0, 0, 0, 0, 0),
                   0, w, bb, A.outp, isbf, gwave, lane);
        gbar(W->bar, ep);
        // s2: T2 = A T1
        spmm_phase(mkjob(W->cnt_u, W->idx_u, ELL_U, NU, W->T1u[layer], W->T2u[layer],
                         0, 0, 0, 0, 0, 0, 0, 0),
                   mkjob(W->cnt_i, W->idx_i, ELL_I, NI, W->T1i[layer], W->T2i[layer],
                         0, 0, 0, 0, 0, 0, 0, 0),
                   0, w, bb, A.outp, isbf, gwave, lane);
        gbar(W->bar, ep);
        // s3: T3 = de2sq o (A^T T2)
        spmm_phase(mkjob(W->cnt_i, W->idx_i, ELL_I, NI, W->T2u[layer], W->T3u[layer],
                         W->de2sq_u, 0, 0, 0, 0, 0, 0, 0),
                   mkjob(W->cnt_u, W->idx_u, ELL_U, NU, W->T2i[layer], W->T3i[layer],
                         W->de2sq_i, 0, 0, 0, 0, 0, 0, 0),
                   1, w, bb, A.outp, isbf, gwave, lane);
        gbar(W->bar, ep);
        // s4: T4 = A T3
        spmm_phase(mkjob(W->cnt_u, W->idx_u, ELL_U, NU, W->T3u[layer], W->T4u[layer],
                         0, 0, 0, 0, 0, 0, 0, 0),
                   mkjob(W->cnt_i, W->idx_i, ELL_I, NI, W->T3i[layer], W->T4i[layer],
                         0, 0, 0, 0, 0, 0, 0, 0),
                   0, w, bb, A.outp, isbf, gwave, lane);
        gbar(W->bar, ep);
        // s5: S = A^T T4 + de1sq o T1
        spmm_phase(mkjob(W->cnt_i, W->idx_i, ELL_I, NI, W->T4u[layer], W->Su[layer],
                         W->de1sq_u, W->T1u[layer], 0, 0, 0, 0, 0, 0),
                   mkjob(W->cnt_u, W->idx_u, ELL_U, NU, W->T4i[layer], W->Si[layer],
                         W->de1sq_i, W->T1i[layer], 0, 0, 0, 0, 0, 0),
                   2, w, bb, A.outp, isbf, gwave, lane);
        gbar(W->bar, ep);
        // s6: M = dv o (A S) + X ; Xnext = M w + b ; Xs' = dv o Xnext ; emit out
        spmm_phase(mkjob(W->cnt_u, W->idx_u, ELL_U, NU, W->Su[layer], 0, 0, 0,
                         W->Xu[layer], W->dv_u, W->Xu[layer + 1], W->Xsu[layer + 1],
                         0, coloff),
                   mkjob(W->cnt_i, W->idx_i, ELL_I, NI, W->Si[layer], 0, 0, 0,
                         W->Xi[layer], W->dv_i, W->Xi[layer + 1], W->Xsi[layer + 1],
                         (size_t)NU * 192, coloff),
                   3, w, bb, A.outp, isbf, gwave, lane);
        if (layer == 0) gbar(W->bar, ep);  // Xu[1]/Xsu[1] feed next layer
    }
}

// ---------------- host ----------------

extern "C" void kernel_launch(void* const* d_in, const int* in_sizes, int n_in,
                              void* d_out, int out_size, void* d_ws, size_t ws_size,
                              hipStream_t stream) {
    FArgs A;
    A.Hp = d_in[0];
    A.ue = d_in[1];
    A.ie = d_in[2];
    A.w0 = d_in[3];
    A.b0 = d_in[4];
    A.w1 = d_in[5];
    A.b1 = d_in[6];
    A.W = (WS*)d_ws;
    A.outp = d_out;
    (void)ws_size; (void)n_in; (void)in_sizes; (void)out_size;

    init_k<<<(NU + NI) / 256, 256, 0, stream>>>(A.W);
    detect_dtype<<<131072 / 256, 256, 0, stream>>>((const u32*)A.Hp, A.W);
    fused<<<NBLK, NTHR, 0, stream>>>(A);
}

// Round 7
// 454.434 us; speedup vs baseline: 5.1519x; 1.1681x over previous
//
#include <hip/hip_runtime.h>
#include <hip/hip_bf16.h>

#define NU 8192
#define NI 4096
#define DE 64
#define ELL_U 80
#define ELL_I 112
#define EPSF 1e-7f

#define NBLK 1024
#define NTHR 256
#define TOTTHR (NBLK * NTHR) /* 262144 threads, 4096 waves */
#define NWAVE (TOTTHR / 64)
#define NGRP 32
#define GRPSZ (NBLK / NGRP) /* 32 */

typedef unsigned int u32;

__device__ __forceinline__ float b2f(__hip_bfloat16 x) { return __bfloat162float(x); }

// sc1 (agent-scope relaxed) store: write-through to the coherent LLC, no dirty
// L2 line. All cross-phase workspace writes use this; consumers use NORMAL
// cached loads, which is sound because every buffer is SSA (written once,
// before first read, never rewritten) -> a consumer's first touch misses L2
// and fetches the final value from the LLC.
template <typename T>
__device__ __forceinline__ void st_dev(T* p, T v) {
    __hip_atomic_store(p, v, __ATOMIC_RELAXED, __HIP_MEMORY_SCOPE_AGENT);
}

// ---- full-SSA workspace layout (compile-time offsets; ~53 MB of 512 MB) ----
struct WS {
    int bar[4096];                       // barrier counters + release words (16 KB)
    int cnt_u[NU]; int cnt_i[NI]; int flag; int pad[63];
    u32 idx_u[NU * ELL_U]; u32 idx_i[NI * ELL_I];
    float a_f[NI]; float p_f[NU]; float b_f[NU]; float q_f[NI];
    float dv_u[NU]; float de1sq_u[NI]; float de2sq_u[NI];
    float dv_i[NI]; float de1sq_i[NU]; float de2sq_i[NU];
    float Xu[3][NU * DE]; float Xsu[3][NU * DE];   // X generations 0,1,2
    float Xi[3][NI * DE]; float Xsi[3][NI * DE];
    float T1u[2][NI * DE]; float T2u[2][NU * DE]; float T3u[2][NI * DE];
    float T4u[2][NU * DE]; float Su[2][NI * DE];   // per-layer fresh temps (u chan)
    float T1i[2][NU * DE]; float T2i[2][NI * DE]; float T3i[2][NU * DE];
    float T4i[2][NI * DE]; float Si[2][NU * DE];   // per-layer fresh temps (i chan)
};

struct Job {
    const int* cnt; const u32* idx; int ell; int nrows;
    const float* src; float* dst; const float* evec; const float* aux;
    const float* xin; const float* dvv; float* xnext; float* xsout;
    size_t obase; int coloff;
};

// ---- grid barrier v7: hierarchical arrive + per-group release broadcast ----
// r6 lesson: 1024 pollers spinning on ONE root line serialize against the
// group-leader RMWs on the same line AND steal fabric bandwidth from the
// stragglers' gathers (~13us/barrier). v7: nobody polls the root. Arrival:
// 32 group counters (128B apart); group-last bumps root (<=32 RMWs); the
// GLOBAL last broadcasts the epoch to 32 per-group release words; each block
// polls its own group's word (32 pollers/line) with s_sleep(16) backoff
// (~0.43us) -> ~75 poll transactions/us/line, negligible.
// bar layout (int idx): root=bar[0]; arrive[g]=bar[128+g*32];
//                       release[g]=bar[2048+g*32].
__device__ __forceinline__ void gbar(int* bar, int& ep) {
    __syncthreads();  // drains vmcnt: all sc1 stores acked at LLC
    ep += 1;
    if (threadIdx.x == 0) {
        int g = blockIdx.x >> 5;  // 32 groups of 32 blocks
        int prev = __hip_atomic_fetch_add(&bar[128 + g * 32], 1, __ATOMIC_RELAXED,
                                          __HIP_MEMORY_SCOPE_AGENT);
        if (prev == ep * GRPSZ - 1) {  // last arriver of this group this epoch
            int pr = __hip_atomic_fetch_add(&bar[0], 1, __ATOMIC_RELAXED,
                                            __HIP_MEMORY_SCOPE_AGENT);
            if (pr == ep * NGRP - 1) {  // global last: broadcast release
#pragma unroll
                for (int g2 = 0; g2 < NGRP; ++g2)
                    __hip_atomic_store(&bar[2048 + g2 * 32], ep, __ATOMIC_RELAXED,
                                       __HIP_MEMORY_SCOPE_AGENT);
            }
        }
        while (__hip_atomic_load(&bar[2048 + g * 32], __ATOMIC_RELAXED,
                                 __HIP_MEMORY_SCOPE_AGENT) < ep)
            __builtin_amdgcn_s_sleep(16);
    }
    asm volatile("" ::: "memory");  // no load hoisting above the spin
    __syncthreads();
}

// scalar per-thread SpMV row (int or float source); normal cached loads
__device__ __forceinline__ float spmv_row(int n, const u32* __restrict__ ip,
                                          const void* __restrict__ s, int isint) {
    float a0 = 0.f, a1 = 0.f, a2 = 0.f, a3 = 0.f;
    int p = 0;
    if (isint) {
        const int* sv = (const int*)s;
        for (; p + 4 <= n; p += 4) {
            uint4 cc = *(const uint4*)(ip + p);
            a0 += (float)sv[cc.x]; a1 += (float)sv[cc.y];
            a2 += (float)sv[cc.z]; a3 += (float)sv[cc.w];
        }
        for (; p < n; p++) a0 += (float)sv[ip[p]];
    } else {
        const float* sv = (const float*)s;
        for (; p + 4 <= n; p += 4) {
            uint4 cc = *(const uint4*)(ip + p);
            a0 += sv[cc.x]; a1 += sv[cc.y]; a2 += sv[cc.z]; a3 += sv[cc.w];
        }
        for (; p < n; p++) a0 += sv[ip[p]];
    }
    return (a0 + a1) + (a2 + a3);
}

// one wave gathers/accumulates one 64-col row; 8 loads in flight; cached loads
__device__ __forceinline__ float gather_row(int n, const u32* __restrict__ ip,
                                            const float* __restrict__ src, int lane) {
    float a0 = 0.f, a1 = 0.f, a2 = 0.f, a3 = 0.f;
    float a4 = 0.f, a5 = 0.f, a6 = 0.f, a7 = 0.f;
    int p = 0;
    if (n >= 8) {
        uint4 cA = *(const uint4*)(ip);
        uint4 cB = *(const uint4*)(ip + 4);
        while (p + 8 <= n) {
            float g0 = src[((size_t)cA.x << 6) + lane];
            float g1 = src[((size_t)cA.y << 6) + lane];
            float g2 = src[((size_t)cA.z << 6) + lane];
            float g3 = src[((size_t)cA.w << 6) + lane];
            float g4 = src[((size_t)cB.x << 6) + lane];
            float g5 = src[((size_t)cB.y << 6) + lane];
            float g6 = src[((size_t)cB.z << 6) + lane];
            float g7 = src[((size_t)cB.w << 6) + lane];
            p += 8;
            // prefetch next batch's indices (overreads <=32B into padding/next row)
            cA = *(const uint4*)(ip + p);
            cB = *(const uint4*)(ip + p + 4);
            a0 += g0; a1 += g1; a2 += g2; a3 += g3;
            a4 += g4; a5 += g5; a6 += g6; a7 += g7;
        }
    }
    if (p + 4 <= n) {
        uint4 cc = *(const uint4*)(ip + p);
        a0 += src[((size_t)cc.x << 6) + lane];
        a1 += src[((size_t)cc.y << 6) + lane];
        a2 += src[((size_t)cc.z << 6) + lane];
        a3 += src[((size_t)cc.w << 6) + lane];
        p += 4;
    }
    for (; p < n; p++) a4 += src[((size_t)ip[p] << 6) + lane];
    return ((a0 + a1) + (a2 + a3)) + ((a4 + a5) + (a6 + a7));
}

// one SpMM phase over both channels; waves grid-stride the 12288 rows
__device__ __forceinline__ void spmm_phase(const Job& j0, const Job& j1, int mode,
                                           const void* w, const void* bias, void* outp,
                                           int isbf, int gwave, int lane) {
    int ntot = j0.nrows + j1.nrows;
    for (int rr = gwave; rr < ntot; rr += NWAVE) {
        bool first = rr < j0.nrows;
        const Job& J = first ? j0 : j1;
        int row = first ? rr : rr - j0.nrows;
        int n = min(J.cnt[row], J.ell);
        const u32* ip = J.idx + (size_t)row * J.ell;
        float acc = gather_row(n, ip, J.src, lane);
        size_t o = ((size_t)row << 6) + lane;
        if (mode == 0) {
            st_dev(J.dst + o, acc);
        } else if (mode == 1) {
            st_dev(J.dst + o, J.evec[row] * acc);
        } else if (mode == 2) {
            st_dev(J.dst + o, acc + J.evec[row] * J.aux[o]);
        } else {
            // M = dv*acc + X ; Xnext = M @ w + b ; emit output in detected dtype
            float dvr = J.dvv[row];
            float m = dvr * acc + J.xin[o];
            float x0, x1 = 0.f, x2 = 0.f, x3 = 0.f;
            if (isbf) {
                const __hip_bfloat16* __restrict__ wp = (const __hip_bfloat16*)w;
                x0 = b2f(((const __hip_bfloat16*)bias)[lane]);
                for (int k = 0; k < 64; k += 4) {
                    x0 = fmaf(__shfl(m, k, 64), b2f(wp[(k << 6) + lane]), x0);
                    x1 = fmaf(__shfl(m, k + 1, 64), b2f(wp[((k + 1) << 6) + lane]), x1);
                    x2 = fmaf(__shfl(m, k + 2, 64), b2f(wp[((k + 2) << 6) + lane]), x2);
                    x3 = fmaf(__shfl(m, k + 3, 64), b2f(wp[((k + 3) << 6) + lane]), x3);
                }
            } else {
                const float* __restrict__ wp = (const float*)w;
                x0 = ((const float*)bias)[lane];
                for (int k = 0; k < 64; k += 4) {
                    x0 = fmaf(__shfl(m, k, 64), wp[(k << 6) + lane], x0);
                    x1 = fmaf(__shfl(m, k + 1, 64), wp[((k + 1) << 6) + lane], x1);
                    x2 = fmaf(__shfl(m, k + 2, 64), wp[((k + 2) << 6) + lane], x2);
                    x3 = fmaf(__shfl(m, k + 3, 64), wp[((k + 3) << 6) + lane], x3);
                }
            }
            float xn = (x0 + x1) + (x2 + x3);
            st_dev(J.xnext + o, xn);
            st_dev(J.xsout + o, dvr * xn);  // dv-premultiplied for next layer's s1
            size_t oo = J.obase + (size_t)row * 192 + J.coloff + lane;
            if (isbf) ((__hip_bfloat16*)outp)[oo] = __float2bfloat16(xn);
            else ((float*)outp)[oo] = xn;
        }
    }
}

__device__ __forceinline__ Job mkjob(const int* cnt, const u32* idx, int ell, int nrows,
                                     const float* src, float* dst, const float* evec,
                                     const float* aux, const float* xin, const float* dvv,
                                     float* xnext, float* xsout, size_t obase, int coloff) {
    Job J;
    J.cnt = cnt; J.idx = idx; J.ell = ell; J.nrows = nrows;
    J.src = src; J.dst = dst; J.evec = evec; J.aux = aux;
    J.xin = xin; J.dvv = dvv; J.xnext = xnext; J.xsout = xsout;
    J.obase = obase; J.coloff = coloff;
    return J;
}

// ---------------- init: zero counters / flag / barrier ----------------

__global__ __launch_bounds__(256) void init_k(WS* W) {
    int t = blockIdx.x * 256 + threadIdx.x;
    if (t == 0) W->flag = 0;
    if (t < 4096) W->bar[t] = 0;
    if (t < NU) W->cnt_u[t] = 0;
    int s = t - NU;
    if (s >= 0 && s < NI) W->cnt_i[s] = 0;
}

// dtype probe: H values are exactly 0.0/1.0. fp32 words are 0x00000000/0x3F800000
// (low u16 always 0). bf16 pairs expose 0x3F80 in the low u16 for even-col nnz.
__global__ __launch_bounds__(256) void detect_dtype(const u32* __restrict__ Hw, WS* W) {
    int t = blockIdx.x * 256 + threadIdx.x;  // 131072 threads
    u32 w = Hw[t];
    if ((w & 0xFFFFu) == 0x3F80u) W->flag = 1;  // benign same-value race
}

// ---------------- the single fused kernel (self-barriered, SSA) ----------------

struct FArgs {
    const void* Hp; const void* ue; const void* ie;
    const void* w0; const void* b0; const void* w1; const void* b1;
    WS* W; void* outp;
};

__global__ __launch_bounds__(NTHR, 4) void fused(FArgs A) {
    WS* W = A.W;
    const int tid = blockIdx.x * NTHR + threadIdx.x;
    const int lane = threadIdx.x & 63;
    const int gwave = tid >> 6;
    int ep = 0;
    const int isbf = W->flag;  // written by detect_dtype (prior dispatch)

    // ---- P2: fill ELL lists for H and H^T (grid-stride, 8 elems/thread/iter) ----
    // cnt via agent atomicAdd (LLC); idx via sc1 stores.
    for (int t = tid; t < NU * NI / 8; t += TOTTHR) {
        int flat = t << 3;
        int i = flat >> 12;    // user row
        int j0 = flat & 4095;  // col base
        u32 words[8];
        if (isbf) {
            uint4 v = ((const uint4*)A.Hp)[t];
            u32 p4[4] = {v.x, v.y, v.z, v.w};
#pragma unroll
            for (int q = 0; q < 4; q++) {
                words[2 * q] = p4[q] & 0xFFFFu;
                words[2 * q + 1] = p4[q] >> 16;
            }
        } else {
            uint4 a = ((const uint4*)A.Hp)[2 * t];
            uint4 b = ((const uint4*)A.Hp)[2 * t + 1];
            words[0] = a.x; words[1] = a.y; words[2] = a.z; words[3] = a.w;
            words[4] = b.x; words[5] = b.y; words[6] = b.z; words[7] = b.w;
        }
#pragma unroll
        for (int e = 0; e < 8; e++) {
            if (words[e]) {
                int j = j0 + e;
                int pu = atomicAdd(&W->cnt_u[i], 1);
                if (pu < ELL_U) st_dev(&W->idx_u[i * ELL_U + pu], (u32)j);
                int pi = atomicAdd(&W->cnt_i[j], 1);
                if (pi < ELL_I) st_dev(&W->idx_i[j * ELL_I + pi], (u32)i);
            }
        }
    }
    gbar(W->bar, ep);

    // ---- P3: a = H^T r (item rows, int src), p = H c (user rows, int src) ----
    if (tid < NI) {
        int n = min(W->cnt_i[tid], ELL_I);
        st_dev(&W->a_f[tid], spmv_row(n, W->idx_i + (size_t)tid * ELL_I, W->cnt_u, 1));
    } else {
        int r = tid - NI;
        if (r < NU) {
            int n = min(W->cnt_u[r], ELL_U);
            st_dev(&W->p_f[r], spmv_row(n, W->idx_u + (size_t)r * ELL_U, W->cnt_i, 1));
        }
    }
    gbar(W->bar, ep);

    // ---- P4: b = H a (user rows), q = H^T p (item rows) ----
    if (tid < NU) {
        int n = min(W->cnt_u[tid], ELL_U);
        st_dev(&W->b_f[tid], spmv_row(n, W->idx_u + (size_t)tid * ELL_U, W->a_f, 0));
    } else {
        int r = tid - NU;
        if (r < NI) {
            int n = min(W->cnt_i[r], ELL_I);
            st_dev(&W->q_f[r], spmv_row(n, W->idx_i + (size_t)r * ELL_I, W->p_f, 0));
        }
    }
    gbar(W->bar, ep);

    // ---- P5: degree vectors + fp32 working copies + layer-0 output cols ----
    if (tid < NU) {
        float r = (float)W->cnt_u[tid];
        float bf_ = W->b_f[tid];
        st_dev(&W->dv_u[tid], 1.0f / sqrtf(r + bf_ + EPSF));
        st_dev(&W->de1sq_i[tid], 1.0f / (r + EPSF));
        st_dev(&W->de2sq_i[tid], 1.0f / (bf_ + EPSF));
    }
    if (tid < NI) {
        float cdeg = (float)W->cnt_i[tid];
        float qf_ = W->q_f[tid];
        st_dev(&W->dv_i[tid], 1.0f / sqrtf(cdeg + qf_ + EPSF));
        st_dev(&W->de1sq_u[tid], 1.0f / (cdeg + EPSF));
        st_dev(&W->de2sq_u[tid], 1.0f / (qf_ + EPSF));
    }
    for (int t = tid; t < (NU + NI) * DE; t += TOTTHR) {
        if (t < NU * DE) {
            int i = t >> 6, l = t & 63;
            float v = isbf ? b2f(((const __hip_bfloat16*)A.ue)[t]) : ((const float*)A.ue)[t];
            st_dev(&W->Xu[0][t], v);
            float dv = 1.0f / sqrtf((float)W->cnt_u[i] + W->b_f[i] + EPSF);
            st_dev(&W->Xsu[0][t], dv * v);
            size_t o = (size_t)i * 192 + l;
            if (isbf) ((__hip_bfloat16*)A.outp)[o] = __float2bfloat16(v);
            else ((float*)A.outp)[o] = v;
        } else {
            int s = t - NU * DE;
            int i = s >> 6, l = s & 63;
            float v = isbf ? b2f(((const __hip_bfloat16*)A.ie)[s]) : ((const float*)A.ie)[s];
            st_dev(&W->Xi[0][s], v);
            float dv = 1.0f / sqrtf((float)W->cnt_i[i] + W->q_f[i] + EPSF);
            st_dev(&W->Xsi[0][s], dv * v);
            size_t o = (size_t)(NU + i) * 192 + l;
            if (isbf) ((__hip_bfloat16*)A.outp)[o] = __float2bfloat16(v);
            else ((float*)A.outp)[o] = v;
        }
    }
    gbar(W->bar, ep);

    // ---- P6..: the 12 SpMM phases (6 per layer, both channels; all SSA) ----
    for (int layer = 0; layer < 2; ++layer) {
        const void* w = layer ? A.w1 : A.w0;
        const void* bb = layer ? A.b1 : A.b0;
        int coloff = 64 + 64 * layer;

        // s1: T1 = A^T Xs
        spmm_phase(mkjob(W->cnt_i, W->idx_i, ELL_I, NI, W->Xsu[layer], W->T1u[layer],
                         0, 0, 0, 0, 0, 0, 0, 0),
                   mkjob(W->cnt_u, W->idx_u, ELL_U, NU, W->Xsi[layer], W->T1i[layer],
                         0, 0, 0, 0, 0, 0, 0, 0),
                   0, w, bb, A.outp, isbf, gwave, lane);
        gbar(W->bar, ep);
        // s2: T2 = A T1
        spmm_phase(mkjob(W->cnt_u, W->idx_u, ELL_U, NU, W->T1u[layer], W->T2u[layer],
                         0, 0, 0, 0, 0, 0, 0, 0),
                   mkjob(W->cnt_i, W->idx_i, ELL_I, NI, W->T1i[layer], W->T2i[layer],
                         0, 0, 0, 0, 0, 0, 0, 0),
                   0, w, bb, A.outp, isbf, gwave, lane);
        gbar(W->bar, ep);
        // s3: T3 = de2sq o (A^T T2)
        spmm_phase(mkjob(W->cnt_i, W->idx_i, ELL_I, NI, W->T2u[layer], W->T3u[layer],
                         W->de2sq_u, 0, 0, 0, 0, 0, 0, 0),
                   mkjob(W->cnt_u, W->idx_u, ELL_U, NU, W->T2i[layer], W->T3i[layer],
                         W->de2sq_i, 0, 0, 0, 0, 0, 0, 0),
                   1, w, bb, A.outp, isbf, gwave, lane);
        gbar(W->bar, ep);
        // s4: T4 = A T3
        spmm_phase(mkjob(W->cnt_u, W->idx_u, ELL_U, NU, W->T3u[layer], W->T4u[layer],
                         0, 0, 0, 0, 0, 0, 0, 0),
                   mkjob(W->cnt_i, W->idx_i, ELL_I, NI, W->T3i[layer], W->T4i[layer],
                         0, 0, 0, 0, 0, 0, 0, 0),
                   0, w, bb, A.outp, isbf, gwave, lane);
        gbar(W->bar, ep);
        // s5: S = A^T T4 + de1sq o T1
        spmm_phase(mkjob(W->cnt_i, W->idx_i, ELL_I, NI, W->T4u[layer], W->Su[layer],
                         W->de1sq_u, W->T1u[layer], 0, 0, 0, 0, 0, 0),
                   mkjob(W->cnt_u, W->idx_u, ELL_U, NU, W->T4i[layer], W->Si[layer],
                         W->de1sq_i, W->T1i[layer], 0, 0, 0, 0, 0, 0),
                   2, w, bb, A.outp, isbf, gwave, lane);
        gbar(W->bar, ep);
        // s6: M = dv o (A S) + X ; Xnext = M w + b ; Xs' = dv o Xnext ; emit out
        spmm_phase(mkjob(W->cnt_u, W->idx_u, ELL_U, NU, W->Su[layer], 0, 0, 0,
                         W->Xu[layer], W->dv_u, W->Xu[layer + 1], W->Xsu[layer + 1],
                         0, coloff),
                   mkjob(W->cnt_i, W->idx_i, ELL_I, NI, W->Si[layer], 0, 0, 0,
                         W->Xi[layer], W->dv_i, W->Xi[layer + 1], W->Xsi[layer + 1],
                         (size_t)NU * 192, coloff),
                   3, w, bb, A.outp, isbf, gwave, lane);
        if (layer == 0) gbar(W->bar, ep);  // Xu[1]/Xsu[1] feed next layer
    }
}

// ---------------- host ----------------

extern "C" void kernel_launch(void* const* d_in, const int* in_sizes, int n_in,
                              void* d_out, int out_size, void* d_ws, size_t ws_size,
                              hipStream_t stream) {
    FArgs A;
    A.Hp = d_in[0];
    A.ue = d_in[1];
    A.ie = d_in[2];
    A.w0 = d_in[3];
    A.b0 = d_in[4];
    A.w1 = d_in[5];
    A.b1 = d_in[6];
    A.W = (WS*)d_ws;
    A.outp = d_out;
    (void)ws_size; (void)n_in; (void)in_sizes; (void)out_size;

    init_k<<<(NU + NI) / 256, 256, 0, stream>>>(A.W);
    detect_dtype<<<131072 / 256, 256, 0, stream>>>((const u32*)A.Hp, A.W);
    fused<<<NBLK, NTHR, 0, stream>>>(A);
}